// Round 1
// baseline (2877.952 us; speedup 1.0000x reference)
//
#include <hip/hip_runtime.h>
#include <cstdint>
#include <cstddef>

#define D 128
#define NODES_TILE 64

// ---------------------------------------------------------------------------
// Detect whether edge_index is int64 (high dwords all zero) or int32.
// Values are in [0, 50000) so int64 high words are always 0; for int32 data
// the probability of 4 consecutive odd words being 0 is ~(2e-5)^4 ~ 0.
// ---------------------------------------------------------------------------
__global__ void detect_dtype(const unsigned int* __restrict__ ei, int* __restrict__ flag) {
    if (threadIdx.x == 0 && blockIdx.x == 0) {
        int is64 = (ei[1] == 0u && ei[3] == 0u && ei[5] == 0u && ei[7] == 0u) ? 1 : 0;
        *flag = is64;
    }
}

// ---------------------------------------------------------------------------
// Grid-stride float4 copy (dst = src)
// ---------------------------------------------------------------------------
__global__ __launch_bounds__(256) void copy_f4(const float4* __restrict__ src,
                                               float4* __restrict__ dst, long long n4) {
    long long i = (long long)blockIdx.x * blockDim.x + threadIdx.x;
    long long stride = (long long)gridDim.x * blockDim.x;
    for (; i < n4; i += stride) dst[i] = src[i];
}

// ---------------------------------------------------------------------------
// Edge-parallel scatter-add: out[dst[e]][:] += X[src[e]][:]
// One thread per (edge, float4-quad): 32 threads per edge, coalesced reads.
// ---------------------------------------------------------------------------
__global__ __launch_bounds__(256) void scatter_add(const float* __restrict__ X,
                                                   const void* __restrict__ ei,
                                                   const int* __restrict__ flag,
                                                   float* __restrict__ out, int E) {
    long long g = (long long)blockIdx.x * 256 + threadIdx.x;
    int e = (int)(g >> 5);
    int q = (int)(g & 31);
    if (e >= E) return;
    int s, d;
    if (*flag) {
        const long long* e64 = (const long long*)ei;
        s = (int)e64[e];
        d = (int)e64[E + e];
    } else {
        const int* e32 = (const int*)ei;
        s = e32[e];
        d = e32[E + e];
    }
    float4 v = ((const float4*)(X + (size_t)s * D))[q];
    float* o = out + (size_t)d * D + q * 4;
    atomicAdd(o + 0, v.x);
    atomicAdd(o + 1, v.y);
    atomicAdd(o + 2, v.z);
    atomicAdd(o + 3, v.w);
}

// ---------------------------------------------------------------------------
// Y = act(X @ W + b), X: M x 128, W: 128 x 128 row-major, fused bias + ReLU.
// Block: 256 threads, 64-row output tile, each thread computes 4 rows x 8 cols.
// X tile staged in LDS (33.8 KB -> 4 blocks/CU); W read via L1/L2 (hot 64 KB).
// ---------------------------------------------------------------------------
template <int RELU>
__global__ __launch_bounds__(256) void gemm128(const float* __restrict__ X,
                                               const float* __restrict__ W,
                                               const float* __restrict__ bias,
                                               float* __restrict__ Y, int M) {
    __shared__ float Xs[NODES_TILE][132];  // +4 pad: rows 16B-aligned, reads 2-way max
    int t = threadIdx.x;
    int row0 = blockIdx.x * NODES_TILE;

    // Stage X tile: 64 rows x 32 float4
    for (int i = t; i < NODES_TILE * 32; i += 256) {
        int r = i >> 5, q = i & 31;
        int row = row0 + r;
        float4 v = make_float4(0.f, 0.f, 0.f, 0.f);
        if (row < M) v = ((const float4*)(X + (size_t)row * D))[q];
        *(float4*)&Xs[r][q * 4] = v;
    }
    __syncthreads();

    int tx = t & 15;   // column group: cols tx*8 .. tx*8+7
    int ty = t >> 4;   // row group:    rows ty*4 .. ty*4+3
    float acc[4][8];
#pragma unroll
    for (int r = 0; r < 4; ++r)
#pragma unroll
        for (int c = 0; c < 8; ++c) acc[r][c] = 0.f;

    const float4* Wv = (const float4*)W;
#pragma unroll 8
    for (int k = 0; k < D; ++k) {
        float4 w0 = Wv[k * 32 + tx * 2];
        float4 w1 = Wv[k * 32 + tx * 2 + 1];
        float wr[8] = {w0.x, w0.y, w0.z, w0.w, w1.x, w1.y, w1.z, w1.w};
#pragma unroll
        for (int r = 0; r < 4; ++r) {
            float xv = Xs[ty * 4 + r][k];
#pragma unroll
            for (int c = 0; c < 8; ++c) acc[r][c] = fmaf(xv, wr[c], acc[r][c]);
        }
    }

    float bv[8];
#pragma unroll
    for (int c = 0; c < 8; ++c) bv[c] = bias[tx * 8 + c];

#pragma unroll
    for (int r = 0; r < 4; ++r) {
        int row = row0 + ty * 4 + r;
        if (row >= M) continue;
        float o[8];
#pragma unroll
        for (int c = 0; c < 8; ++c) {
            float v = acc[r][c] + bv[c];
            o[c] = RELU ? fmaxf(v, 0.f) : v;
        }
        float4* out4 = (float4*)(Y + (size_t)row * D + tx * 8);
        out4[0] = make_float4(o[0], o[1], o[2], o[3]);
        out4[1] = make_float4(o[4], o[5], o[6], o[7]);
    }
}

// ---------------------------------------------------------------------------
// out[i] = sigmoid(dot(H[i,:], Wfc) + bfc), one thread per node
// ---------------------------------------------------------------------------
__global__ __launch_bounds__(256) void final_fc(const float* __restrict__ H,
                                                const float* __restrict__ Wfc,
                                                const float* __restrict__ bfc,
                                                float* __restrict__ out, int M) {
    int i = blockIdx.x * 256 + threadIdx.x;
    if (i >= M) return;
    const float4* h = (const float4*)(H + (size_t)i * D);
    const float4* w = (const float4*)Wfc;
    float s = 0.f;
#pragma unroll
    for (int q = 0; q < 32; ++q) {
        float4 a = h[q];
        float4 b = w[q];
        s = fmaf(a.x, b.x, s);
        s = fmaf(a.y, b.y, s);
        s = fmaf(a.z, b.z, s);
        s = fmaf(a.w, b.w, s);
    }
    s += bfc[0];
    out[i] = 1.f / (1.f + expf(-s));
}

extern "C" void kernel_launch(void* const* d_in, const int* in_sizes, int n_in,
                              void* d_out, int out_size, void* d_ws, size_t ws_size,
                              hipStream_t stream) {
    const float* x   = (const float*)d_in[0];
    const void*  ei  = d_in[1];
    const float* W1a = (const float*)d_in[2];
    const float* b1a = (const float*)d_in[3];
    const float* W1b = (const float*)d_in[4];
    const float* b1b = (const float*)d_in[5];
    const float* W2a = (const float*)d_in[6];
    const float* b2a = (const float*)d_in[7];
    const float* W2b = (const float*)d_in[8];
    const float* b2b = (const float*)d_in[9];
    const float* Wfc = (const float*)d_in[10];
    const float* bfc = (const float*)d_in[11];
    float* out = (float*)d_out;

    int M = in_sizes[0] / D;   // 50000 nodes
    int E = in_sizes[1] / 2;   // 800000 edges
    size_t nf = (size_t)M * D;

    float* bufA = (float*)d_ws;
    float* bufB = bufA + nf;
    int* flag = (int*)(bufB + nf);

    detect_dtype<<<1, 64, 0, stream>>>((const unsigned int*)ei, flag);

    long long n4 = (long long)(nf / 4);
    dim3 gemmGrid((M + NODES_TILE - 1) / NODES_TILE);
    long long scatterThreads = (long long)E * 32;
    int scatterBlocks = (int)((scatterThreads + 255) / 256);

    // ---- layer 1: bufA = x + scatter(x); bufB = relu(bufA@W1a+b1a); bufA = relu(bufB@W1b+b1b)
    copy_f4<<<2048, 256, 0, stream>>>((const float4*)x, (float4*)bufA, n4);
    scatter_add<<<scatterBlocks, 256, 0, stream>>>(x, ei, flag, bufA, E);
    gemm128<1><<<gemmGrid, 256, 0, stream>>>(bufA, W1a, b1a, bufB, M);
    gemm128<1><<<gemmGrid, 256, 0, stream>>>(bufB, W1b, b1b, bufA, M);

    // ---- layer 2: bufB = h1 + scatter(h1); bufA = relu(bufB@W2a+b2a); bufB = relu(bufA@W2b+b2b)
    copy_f4<<<2048, 256, 0, stream>>>((const float4*)bufA, (float4*)bufB, n4);
    scatter_add<<<scatterBlocks, 256, 0, stream>>>(bufA, ei, flag, bufB, E);
    gemm128<1><<<gemmGrid, 256, 0, stream>>>(bufB, W2a, b2a, bufA, M);
    gemm128<1><<<gemmGrid, 256, 0, stream>>>(bufA, W2b, b2b, bufB, M);

    // ---- readout
    final_fc<<<(M + 255) / 256, 256, 0, stream>>>(bufB, Wfc, bfc, out, M);
}

// Round 2
// 442.628 us; speedup vs baseline: 6.5020x; 6.5020x over previous
//
#include <hip/hip_runtime.h>
#include <cstdint>
#include <cstddef>

#define D 128
#define NODES_TILE 64

// ---------------------------------------------------------------------------
// Detect whether edge_index is int64 (high dwords all zero) or int32.
// Values are in [0, 50000) so int64 high words are always 0; for int32 data
// the probability of 4 consecutive odd words being 0 is ~(2e-5)^4 ~ 0.
// ---------------------------------------------------------------------------
__global__ void detect_dtype(const unsigned int* __restrict__ ei, int* __restrict__ flag) {
    if (threadIdx.x == 0 && blockIdx.x == 0) {
        int is64 = (ei[1] == 0u && ei[3] == 0u && ei[5] == 0u && ei[7] == 0u) ? 1 : 0;
        *flag = is64;
    }
}

__device__ __forceinline__ void load_edge(const void* ei, int flag, int E, int e,
                                          int& s, int& d) {
    if (flag) {
        const long long* e64 = (const long long*)ei;
        s = (int)e64[e];
        d = (int)e64[E + e];
    } else {
        const int* e32 = (const int*)ei;
        s = e32[e];
        d = e32[E + e];
    }
}

// ---------------------------------------------------------------------------
// CSR build: count -> scan -> fill
// ---------------------------------------------------------------------------
__global__ __launch_bounds__(256) void zero_int(int* __restrict__ p, int n) {
    int i = blockIdx.x * 256 + threadIdx.x;
    if (i < n) p[i] = 0;
}

__global__ __launch_bounds__(256) void count_edges(const void* __restrict__ ei,
                                                   const int* __restrict__ flag,
                                                   int* __restrict__ cnt, int E) {
    int e = blockIdx.x * 256 + threadIdx.x;
    if (e >= E) return;
    int s, d;
    load_edge(ei, *flag, E, e, s, d);
    atomicAdd(&cnt[d], 1);
}

__global__ __launch_bounds__(256) void block_sums(const int* __restrict__ cnt,
                                                  int* __restrict__ bsum, int n) {
    __shared__ int sm[256];
    int i = blockIdx.x * 256 + threadIdx.x;
    sm[threadIdx.x] = (i < n) ? cnt[i] : 0;
    __syncthreads();
    for (int off = 128; off > 0; off >>= 1) {
        if (threadIdx.x < off) sm[threadIdx.x] += sm[threadIdx.x + off];
        __syncthreads();
    }
    if (threadIdx.x == 0) bsum[blockIdx.x] = sm[0];
}

// single wave: in-place exclusive scan of nb (<=512) block sums
__global__ __launch_bounds__(64) void scan_bsums(int* __restrict__ bsum, int nb) {
    int lane = threadIdx.x;
    int per = (nb + 63) / 64;
    int loc[8];
    int s = 0;
    for (int k = 0; k < per; ++k) {
        int v = (lane * per + k < nb) ? bsum[lane * per + k] : 0;
        loc[k] = s;
        s += v;
    }
    int incl = s;
    for (int off = 1; off < 64; off <<= 1) {
        int t = __shfl_up(incl, off);
        if (lane >= off) incl += t;
    }
    int ex = incl - s;
    for (int k = 0; k < per; ++k)
        if (lane * per + k < nb) bsum[lane * per + k] = ex + loc[k];
}

__global__ __launch_bounds__(256) void block_scan_apply(const int* __restrict__ cnt,
                                                        const int* __restrict__ bsum,
                                                        int* __restrict__ offs,
                                                        int* __restrict__ cursor, int n) {
    __shared__ int sm[256];
    int i = blockIdx.x * 256 + threadIdx.x;
    int v = (i < n) ? cnt[i] : 0;
    sm[threadIdx.x] = v;
    __syncthreads();
    for (int off = 1; off < 256; off <<= 1) {
        int t = (threadIdx.x >= off) ? sm[threadIdx.x - off] : 0;
        __syncthreads();
        sm[threadIdx.x] += t;
        __syncthreads();
    }
    int excl = bsum[blockIdx.x] + sm[threadIdx.x] - v;
    if (i < n) {
        offs[i] = excl;
        cursor[i] = excl;
    }
}

__global__ __launch_bounds__(256) void fill_csr(const void* __restrict__ ei,
                                                const int* __restrict__ flag,
                                                int* __restrict__ cursor,
                                                int* __restrict__ csr, int E) {
    int e = blockIdx.x * 256 + threadIdx.x;
    if (e >= E) return;
    int s, d;
    load_edge(ei, *flag, E, e, s, d);
    int pos = atomicAdd(&cursor[d], 1);
    csr[pos] = s;
}

// ---------------------------------------------------------------------------
// Gather-aggregate: H[i] = X[i] + sum_{j in in(i)} X[j].  One 64-lane wave per
// node; each lane owns a float2 column slice (64*8B = 512B coalesced rows).
// ---------------------------------------------------------------------------
__global__ __launch_bounds__(256) void aggregate(const float* __restrict__ X,
                                                 const int* __restrict__ offs,
                                                 const int* __restrict__ cnt,
                                                 const int* __restrict__ csr,
                                                 float* __restrict__ H, int M) {
    int wid = (int)((blockIdx.x * 256 + threadIdx.x) >> 6);
    int lane = threadIdx.x & 63;
    if (wid >= M) return;
    int beg = offs[wid];
    int deg = cnt[wid];
    const float2* Xv = (const float2*)X;
    float2 a = Xv[(size_t)wid * 64 + lane];
    for (int j = 0; j < deg; ++j) {
        int s = csr[beg + j];
        float2 v = Xv[(size_t)s * 64 + lane];
        a.x += v.x;
        a.y += v.y;
    }
    ((float2*)H)[(size_t)wid * 64 + lane] = a;
}

// ---------------------------------------------------------------------------
// Y = act(X @ W + b), X: M x 128, W: 128 x 128 row-major, fused bias + ReLU.
// ---------------------------------------------------------------------------
template <int RELU>
__global__ __launch_bounds__(256) void gemm128(const float* __restrict__ X,
                                               const float* __restrict__ W,
                                               const float* __restrict__ bias,
                                               float* __restrict__ Y, int M) {
    __shared__ float Xs[NODES_TILE][132];
    int t = threadIdx.x;
    int row0 = blockIdx.x * NODES_TILE;

    for (int i = t; i < NODES_TILE * 32; i += 256) {
        int r = i >> 5, q = i & 31;
        int row = row0 + r;
        float4 v = make_float4(0.f, 0.f, 0.f, 0.f);
        if (row < M) v = ((const float4*)(X + (size_t)row * D))[q];
        *(float4*)&Xs[r][q * 4] = v;
    }
    __syncthreads();

    int tx = t & 15;
    int ty = t >> 4;
    float acc[4][8];
#pragma unroll
    for (int r = 0; r < 4; ++r)
#pragma unroll
        for (int c = 0; c < 8; ++c) acc[r][c] = 0.f;

    const float4* Wv = (const float4*)W;
#pragma unroll 8
    for (int k = 0; k < D; ++k) {
        float4 w0 = Wv[k * 32 + tx * 2];
        float4 w1 = Wv[k * 32 + tx * 2 + 1];
        float wr[8] = {w0.x, w0.y, w0.z, w0.w, w1.x, w1.y, w1.z, w1.w};
#pragma unroll
        for (int r = 0; r < 4; ++r) {
            float xv = Xs[ty * 4 + r][k];
#pragma unroll
            for (int c = 0; c < 8; ++c) acc[r][c] = fmaf(xv, wr[c], acc[r][c]);
        }
    }

    float bv[8];
#pragma unroll
    for (int c = 0; c < 8; ++c) bv[c] = bias[tx * 8 + c];

#pragma unroll
    for (int r = 0; r < 4; ++r) {
        int row = row0 + ty * 4 + r;
        if (row >= M) continue;
        float o[8];
#pragma unroll
        for (int c = 0; c < 8; ++c) {
            float v = acc[r][c] + bv[c];
            o[c] = RELU ? fmaxf(v, 0.f) : v;
        }
        float4* out4 = (float4*)(Y + (size_t)row * D + tx * 8);
        out4[0] = make_float4(o[0], o[1], o[2], o[3]);
        out4[1] = make_float4(o[4], o[5], o[6], o[7]);
    }
}

// ---------------------------------------------------------------------------
// out[i] = sigmoid(dot(H[i,:], Wfc) + bfc)
// ---------------------------------------------------------------------------
__global__ __launch_bounds__(256) void final_fc(const float* __restrict__ H,
                                                const float* __restrict__ Wfc,
                                                const float* __restrict__ bfc,
                                                float* __restrict__ out, int M) {
    int i = blockIdx.x * 256 + threadIdx.x;
    if (i >= M) return;
    const float4* h = (const float4*)(H + (size_t)i * D);
    const float4* w = (const float4*)Wfc;
    float s = 0.f;
#pragma unroll
    for (int q = 0; q < 32; ++q) {
        float4 a = h[q];
        float4 b = w[q];
        s = fmaf(a.x, b.x, s);
        s = fmaf(a.y, b.y, s);
        s = fmaf(a.z, b.z, s);
        s = fmaf(a.w, b.w, s);
    }
    s += bfc[0];
    out[i] = 1.f / (1.f + expf(-s));
}

extern "C" void kernel_launch(void* const* d_in, const int* in_sizes, int n_in,
                              void* d_out, int out_size, void* d_ws, size_t ws_size,
                              hipStream_t stream) {
    const float* x   = (const float*)d_in[0];
    const void*  ei  = d_in[1];
    const float* W1a = (const float*)d_in[2];
    const float* b1a = (const float*)d_in[3];
    const float* W1b = (const float*)d_in[4];
    const float* b1b = (const float*)d_in[5];
    const float* W2a = (const float*)d_in[6];
    const float* b2a = (const float*)d_in[7];
    const float* W2b = (const float*)d_in[8];
    const float* b2b = (const float*)d_in[9];
    const float* Wfc = (const float*)d_in[10];
    const float* bfc = (const float*)d_in[11];
    float* out = (float*)d_out;

    int M = in_sizes[0] / D;   // 50000
    int E = in_sizes[1] / 2;   // 800000
    size_t nf = (size_t)M * D;

    // workspace layout
    float* bufA = (float*)d_ws;
    float* bufB = bufA + nf;
    int* cnt    = (int*)(bufB + nf);
    int* offs   = cnt + M;
    int* cursor = offs + M;
    int* csr    = cursor + M;
    int* flag   = csr + E;
    int nb = (M + 255) / 256;
    int* bsum   = flag + 1;     // nb ints

    int eBlocks = (E + 255) / 256;
    int mBlocks = (M + 255) / 256;
    dim3 gemmGrid((M + NODES_TILE - 1) / NODES_TILE);
    int aggBlocks = (int)(((long long)M * 64 + 255) / 256);

    // ---- CSR build (once, reused by both layers)
    detect_dtype<<<1, 64, 0, stream>>>((const unsigned int*)ei, flag);
    zero_int<<<mBlocks, 256, 0, stream>>>(cnt, M);
    count_edges<<<eBlocks, 256, 0, stream>>>(ei, flag, cnt, E);
    block_sums<<<nb, 256, 0, stream>>>(cnt, bsum, M);
    scan_bsums<<<1, 64, 0, stream>>>(bsum, nb);
    block_scan_apply<<<nb, 256, 0, stream>>>(cnt, bsum, offs, cursor, M);
    fill_csr<<<eBlocks, 256, 0, stream>>>(ei, flag, cursor, csr, E);

    // ---- layer 1
    aggregate<<<aggBlocks, 256, 0, stream>>>(x, offs, cnt, csr, bufA, M);
    gemm128<1><<<gemmGrid, 256, 0, stream>>>(bufA, W1a, b1a, bufB, M);
    gemm128<1><<<gemmGrid, 256, 0, stream>>>(bufB, W1b, b1b, bufA, M);

    // ---- layer 2
    aggregate<<<aggBlocks, 256, 0, stream>>>(bufA, offs, cnt, csr, bufB, M);
    gemm128<1><<<gemmGrid, 256, 0, stream>>>(bufB, W2a, b2a, bufA, M);
    gemm128<1><<<gemmGrid, 256, 0, stream>>>(bufA, W2b, b2b, bufB, M);

    // ---- readout
    final_fc<<<mBlocks, 256, 0, stream>>>(bufB, Wfc, bfc, out, M);
}

// Round 3
// 393.819 us; speedup vs baseline: 7.3078x; 1.1239x over previous
//
#include <hip/hip_runtime.h>
#include <hip/hip_bf16.h>
#include <cstdint>
#include <cstddef>

#define D 128
typedef __attribute__((ext_vector_type(8))) short short8;
typedef __attribute__((ext_vector_type(4))) float f32x4;

__device__ __forceinline__ float bf2f(ushort u) {
    union { uint i; float f; } v; v.i = ((uint)u) << 16; return v.f;
}
__device__ __forceinline__ ushort f2bf(float f) {
    uint x = __float_as_uint(f);
    uint r = (x + 0x7fffu + ((x >> 16) & 1u)) >> 16;   // RNE
    return (ushort)r;
}

// ---------------------------------------------------------------------------
// Edge dtype probe: int64 (odd dwords zero) vs int32
// ---------------------------------------------------------------------------
__global__ void detect_dtype(const unsigned int* __restrict__ ei, int* __restrict__ flag) {
    if (threadIdx.x == 0 && blockIdx.x == 0) {
        int is64 = (ei[1] == 0u && ei[3] == 0u && ei[5] == 0u && ei[7] == 0u) ? 1 : 0;
        *flag = is64;
    }
}

__device__ __forceinline__ void load_edge(const void* ei, int flag, int E, int e,
                                          int& s, int& d) {
    if (flag) {
        const long long* e64 = (const long long*)ei;
        s = (int)e64[e];
        d = (int)e64[E + e];
    } else {
        const int* e32 = (const int*)ei;
        s = e32[e];
        d = e32[E + e];
    }
}

// ---------------------------------------------------------------------------
// CSR build: count -> scan -> fill  (built once, reused by both layers)
// ---------------------------------------------------------------------------
__global__ __launch_bounds__(256) void zero_int(int* __restrict__ p, int n) {
    int i = blockIdx.x * 256 + threadIdx.x;
    if (i < n) p[i] = 0;
}

__global__ __launch_bounds__(256) void count_edges(const void* __restrict__ ei,
                                                   const int* __restrict__ flag,
                                                   int* __restrict__ cnt, int E) {
    int e = blockIdx.x * 256 + threadIdx.x;
    if (e >= E) return;
    int s, d;
    load_edge(ei, *flag, E, e, s, d);
    atomicAdd(&cnt[d], 1);
}

__global__ __launch_bounds__(256) void block_sums(const int* __restrict__ cnt,
                                                  int* __restrict__ bsum, int n) {
    __shared__ int sm[256];
    int i = blockIdx.x * 256 + threadIdx.x;
    sm[threadIdx.x] = (i < n) ? cnt[i] : 0;
    __syncthreads();
    for (int off = 128; off > 0; off >>= 1) {
        if (threadIdx.x < off) sm[threadIdx.x] += sm[threadIdx.x + off];
        __syncthreads();
    }
    if (threadIdx.x == 0) bsum[blockIdx.x] = sm[0];
}

__global__ __launch_bounds__(64) void scan_bsums(int* __restrict__ bsum, int nb) {
    int lane = threadIdx.x;
    int per = (nb + 63) / 64;
    int loc[8];
    int s = 0;
    for (int k = 0; k < per; ++k) {
        int v = (lane * per + k < nb) ? bsum[lane * per + k] : 0;
        loc[k] = s;
        s += v;
    }
    int incl = s;
    for (int off = 1; off < 64; off <<= 1) {
        int t = __shfl_up(incl, off);
        if (lane >= off) incl += t;
    }
    int ex = incl - s;
    for (int k = 0; k < per; ++k)
        if (lane * per + k < nb) bsum[lane * per + k] = ex + loc[k];
}

__global__ __launch_bounds__(256) void block_scan_apply(const int* __restrict__ cnt,
                                                        const int* __restrict__ bsum,
                                                        int* __restrict__ offs,
                                                        int* __restrict__ cursor, int n) {
    __shared__ int sm[256];
    int i = blockIdx.x * 256 + threadIdx.x;
    int v = (i < n) ? cnt[i] : 0;
    sm[threadIdx.x] = v;
    __syncthreads();
    for (int off = 1; off < 256; off <<= 1) {
        int t = (threadIdx.x >= off) ? sm[threadIdx.x - off] : 0;
        __syncthreads();
        sm[threadIdx.x] += t;
        __syncthreads();
    }
    int excl = bsum[blockIdx.x] + sm[threadIdx.x] - v;
    if (i < n) {
        offs[i] = excl;
        cursor[i] = excl;
    }
}

__global__ __launch_bounds__(256) void fill_csr(const void* __restrict__ ei,
                                                const int* __restrict__ flag,
                                                int* __restrict__ cursor,
                                                int* __restrict__ csr, int E) {
    int e = blockIdx.x * 256 + threadIdx.x;
    if (e >= E) return;
    int s, d;
    load_edge(ei, *flag, E, e, s, d);
    int pos = atomicAdd(&cursor[d], 1);
    csr[pos] = s;
}

// ---------------------------------------------------------------------------
// x (fp32 row-major) -> chunked bf16 [4][M][32]
// ---------------------------------------------------------------------------
__global__ __launch_bounds__(256) void convert_x(const float* __restrict__ x,
                                                 ushort* __restrict__ Xc, int M) {
    long long gid = (long long)blockIdx.x * 256 + threadIdx.x;
    if (gid >= (long long)M * 64) return;
    int node = (int)(gid >> 6), c2 = (int)(gid & 63);
    float2 v = *(const float2*)(x + (size_t)node * D + c2 * 2);
    int chunk = c2 >> 4;
    uint o = (uint)f2bf(v.x) | ((uint)f2bf(v.y) << 16);
    ((uint*)Xc)[(size_t)chunk * M * 16 + (size_t)node * 16 + (c2 & 15)] = o;
}

// ---------------------------------------------------------------------------
// Pack 4 weight matrices (fp32 [128][128] row-major) into bf16 MFMA B-fragment
// order: P[((ks*128 + n)*4 + g)*8 + j] = W[(ks*32+g*8+j)*128 + n]
// grid = 4*64 blocks; blockIdx>>6 selects the matrix.
// ---------------------------------------------------------------------------
__global__ __launch_bounds__(256) void pack_weights(const float* __restrict__ W0,
                                                    const float* __restrict__ W1,
                                                    const float* __restrict__ W2,
                                                    const float* __restrict__ W3,
                                                    ushort* __restrict__ P0,
                                                    ushort* __restrict__ P1,
                                                    ushort* __restrict__ P2,
                                                    ushort* __restrict__ P3) {
    int o = (blockIdx.x & 63) * 256 + threadIdx.x;  // 0..16383
    int which = blockIdx.x >> 6;
    const float* W = which == 0 ? W0 : which == 1 ? W1 : which == 2 ? W2 : W3;
    ushort* P = which == 0 ? P0 : which == 1 ? P1 : which == 2 ? P2 : P3;
    int j = o & 7, g = (o >> 3) & 3, n = (o >> 5) & 127, ks = o >> 12;
    int k = ks * 32 + g * 8 + j;
    P[o] = f2bf(W[k * 128 + n]);
}

// ---------------------------------------------------------------------------
// Chunked gather-aggregate: Hc[c][i] = Xc[c][i] + sum_{j in in(i)} Xc[c][j]
// One wave per (node, chunk); chunk-major wave order keeps the 3.2 MB chunk
// L2-resident per XCD. 4 edges in flight (16 lanes x bf16x2 each), fp32 acc.
// ---------------------------------------------------------------------------
__global__ __launch_bounds__(256) void aggregate_bf16(const ushort* __restrict__ Xc,
                                                      const int* __restrict__ offs,
                                                      const int* __restrict__ cnt,
                                                      const int* __restrict__ csr,
                                                      ushort* __restrict__ Hc, int M) {
    long long gid = (long long)blockIdx.x * 256 + threadIdx.x;
    int w = (int)(gid >> 6);
    if (w >= 4 * M) return;
    int lane = threadIdx.x & 63;
    int sub = lane >> 4, c16 = lane & 15;
    int chunk = w / M;
    int node = w - chunk * M;
    const uint* base = (const uint*)Xc + (size_t)chunk * M * 16;
    int beg = offs[node], deg = cnt[node];
    float ax = 0.f, ay = 0.f;
    for (int j0 = 0; j0 < deg; j0 += 4) {
        int e = j0 + sub;
        if (e < deg) {
            int s = csr[beg + e];
            uint u = base[(size_t)s * 16 + c16];
            ax += bf2f((ushort)(u & 0xffff));
            ay += bf2f((ushort)(u >> 16));
        }
    }
    ax += __shfl_xor(ax, 16); ay += __shfl_xor(ay, 16);
    ax += __shfl_xor(ax, 32); ay += __shfl_xor(ay, 32);
    uint su = base[(size_t)node * 16 + c16];
    ax += bf2f((ushort)(su & 0xffff));
    ay += bf2f((ushort)(su >> 16));
    if (sub == 0) {
        uint o = (uint)f2bf(ax) | ((uint)f2bf(ay) << 16);
        ((uint*)Hc)[(size_t)chunk * M * 16 + (size_t)node * 16 + c16] = o;
    }
}

// ---------------------------------------------------------------------------
// C = relu(A @ W + b) via mfma_f32_16x16x32_bf16.
// A, C: chunked bf16 [4][M][32] (chunk == k-step for A, so frag loads are 16B).
// Bp: packed fragment-order weights. 4 waves/block, 16 rows/wave, 64 rows/blk.
// ---------------------------------------------------------------------------
template <int RELU>
__global__ __launch_bounds__(256) void gemm_mfma(const ushort* __restrict__ A,
                                                 const ushort* __restrict__ Bp,
                                                 const float* __restrict__ bias,
                                                 ushort* __restrict__ C, int M) {
    int t = threadIdx.x;
    int wv = t >> 6, lane = t & 63;
    int l15 = lane & 15, g = lane >> 4;
    int row_base = blockIdx.x * 64 + wv * 16;
    int arow = row_base + l15;
    int arow_c = arow < M ? arow : M - 1;

    f32x4 acc[8];
#pragma unroll
    for (int i = 0; i < 8; ++i) acc[i] = (f32x4){0.f, 0.f, 0.f, 0.f};

#pragma unroll
    for (int ks = 0; ks < 4; ++ks) {
        short8 a = *(const short8*)(A + (size_t)ks * M * 32 + (size_t)arow_c * 32 + g * 8);
#pragma unroll
        for (int nt = 0; nt < 8; ++nt) {
            short8 b = *(const short8*)(Bp + (((ks * 128 + nt * 16 + l15) * 4 + g) << 3));
            acc[nt] = __builtin_amdgcn_mfma_f32_16x16x32_bf16(a, b, acc[nt], 0, 0, 0);
        }
    }

#pragma unroll
    for (int nt = 0; nt < 8; ++nt) {
        int col = nt * 16 + l15;
        float bv = bias[col];
        int chunk = col >> 5, cc = col & 31;
#pragma unroll
        for (int r = 0; r < 4; ++r) {
            int row = row_base + g * 4 + r;
            if (row < M) {
                float v = acc[nt][r] + bv;
                if (RELU) v = fmaxf(v, 0.f);
                C[(size_t)chunk * M * 32 + (size_t)row * 32 + cc] = f2bf(v);
            }
        }
    }
}

// ---------------------------------------------------------------------------
// out[i] = sigmoid(dot(H[i,:], Wfc) + bfc), H chunked bf16
// ---------------------------------------------------------------------------
__global__ __launch_bounds__(256) void final_fc(const ushort* __restrict__ H,
                                                const float* __restrict__ Wfc,
                                                const float* __restrict__ bfc,
                                                float* __restrict__ out, int M) {
    int i = blockIdx.x * 256 + threadIdx.x;
    if (i >= M) return;
    float s = 0.f;
#pragma unroll
    for (int c = 0; c < 4; ++c) {
        const uint* p = (const uint*)H + (size_t)c * M * 16 + (size_t)i * 16;
#pragma unroll
        for (int q = 0; q < 16; ++q) {
            uint u = p[q];
            s = fmaf(bf2f((ushort)(u & 0xffff)), Wfc[c * 32 + 2 * q], s);
            s = fmaf(bf2f((ushort)(u >> 16)), Wfc[c * 32 + 2 * q + 1], s);
        }
    }
    s += bfc[0];
    out[i] = 1.f / (1.f + expf(-s));
}

extern "C" void kernel_launch(void* const* d_in, const int* in_sizes, int n_in,
                              void* d_out, int out_size, void* d_ws, size_t ws_size,
                              hipStream_t stream) {
    const float* x   = (const float*)d_in[0];
    const void*  ei  = d_in[1];
    const float* W1a = (const float*)d_in[2];
    const float* b1a = (const float*)d_in[3];
    const float* W1b = (const float*)d_in[4];
    const float* b1b = (const float*)d_in[5];
    const float* W2a = (const float*)d_in[6];
    const float* b2a = (const float*)d_in[7];
    const float* W2b = (const float*)d_in[8];
    const float* b2b = (const float*)d_in[9];
    const float* Wfc = (const float*)d_in[10];
    const float* bfc = (const float*)d_in[11];
    float* out = (float*)d_out;

    int M = in_sizes[0] / D;   // 50000
    int E = in_sizes[1] / 2;   // 800000
    size_t nf = (size_t)M * D;

    // workspace layout
    ushort* B0 = (ushort*)d_ws;          // chunked bf16 [4][M][32]
    ushort* B1 = B0 + nf;
    ushort* B2 = B1 + nf;
    ushort* P1a = B2 + nf;               // 4 x 16384 packed weights
    ushort* P1b = P1a + 16384;
    ushort* P2a = P1b + 16384;
    ushort* P2b = P2a + 16384;
    int* cnt    = (int*)(P2b + 16384);
    int* offs   = cnt + M;
    int* cursor = offs + M;
    int* csr    = cursor + M;
    int* flag   = csr + E;
    int nb = (M + 255) / 256;
    int* bsum   = flag + 1;

    int eBlocks = (E + 255) / 256;
    int mBlocks = (M + 255) / 256;
    int cvtBlocks = (int)(((long long)M * 64 + 255) / 256);
    int aggBlocks = (int)((4LL * M * 64 + 255) / 256);
    dim3 gemmGrid((M + 63) / 64);

    // ---- CSR build (once)
    detect_dtype<<<1, 64, 0, stream>>>((const unsigned int*)ei, flag);
    zero_int<<<mBlocks, 256, 0, stream>>>(cnt, M);
    count_edges<<<eBlocks, 256, 0, stream>>>(ei, flag, cnt, E);
    block_sums<<<nb, 256, 0, stream>>>(cnt, bsum, M);
    scan_bsums<<<1, 64, 0, stream>>>(bsum, nb);
    block_scan_apply<<<nb, 256, 0, stream>>>(cnt, bsum, offs, cursor, M);
    fill_csr<<<eBlocks, 256, 0, stream>>>(ei, flag, cursor, csr, E);

    // ---- precompute bf16 inputs / packed weights
    convert_x<<<cvtBlocks, 256, 0, stream>>>(x, B0, M);
    pack_weights<<<256, 256, 0, stream>>>(W1a, W1b, W2a, W2b, P1a, P1b, P2a, P2b);

    // ---- layer 1
    aggregate_bf16<<<aggBlocks, 256, 0, stream>>>(B0, offs, cnt, csr, B1, M);
    gemm_mfma<1><<<gemmGrid, 256, 0, stream>>>(B1, P1a, b1a, B2, M);
    gemm_mfma<1><<<gemmGrid, 256, 0, stream>>>(B2, P1b, b1b, B1, M);

    // ---- layer 2
    aggregate_bf16<<<aggBlocks, 256, 0, stream>>>(B1, offs, cnt, csr, B2, M);
    gemm_mfma<1><<<gemmGrid, 256, 0, stream>>>(B2, P2a, b2a, B0, M);
    gemm_mfma<1><<<gemmGrid, 256, 0, stream>>>(B0, P2b, b2b, B2, M);

    // ---- readout
    final_fc<<<mBlocks, 256, 0, stream>>>(B2, Wfc, bfc, out, M);
}

// Round 4
// 292.459 us; speedup vs baseline: 9.8405x; 1.3466x over previous
//
#include <hip/hip_runtime.h>
#include <hip/hip_bf16.h>
#include <cstdint>
#include <cstddef>

#define D 128
typedef __attribute__((ext_vector_type(8))) short short8;
typedef __attribute__((ext_vector_type(4))) float f32x4;

__device__ __forceinline__ float bf2f(ushort u) {
    union { uint i; float f; } v; v.i = ((uint)u) << 16; return v.f;
}
__device__ __forceinline__ ushort f2bf(float f) {
    uint x = __float_as_uint(f);
    uint r = (x + 0x7fffu + ((x >> 16) & 1u)) >> 16;   // RNE
    return (ushort)r;
}

// ---------------------------------------------------------------------------
// zero degree counters + edge dtype probe (int64 has odd dwords == 0)
// ---------------------------------------------------------------------------
__global__ __launch_bounds__(256) void zero_detect(int* __restrict__ cnt, int n,
                                                   const unsigned int* __restrict__ ei,
                                                   int* __restrict__ flag) {
    int i = blockIdx.x * 256 + threadIdx.x;
    if (i < n) cnt[i] = 0;
    if (i == 0) {
        int is64 = (ei[1] == 0u && ei[3] == 0u && ei[5] == 0u && ei[7] == 0u) ? 1 : 0;
        *flag = is64;
    }
}

__device__ __forceinline__ void load_edge(const void* ei, int flag, int E, int e,
                                          int& s, int& d) {
    if (flag) {
        const long long* e64 = (const long long*)ei;
        s = (int)e64[e];
        d = (int)e64[E + e];
    } else {
        const int* e32 = (const int*)ei;
        s = e32[e];
        d = e32[E + e];
    }
}

__global__ __launch_bounds__(256) void count_edges(const void* __restrict__ ei,
                                                   const int* __restrict__ flag,
                                                   int* __restrict__ cnt, int E) {
    int e = blockIdx.x * 256 + threadIdx.x;
    if (e >= E) return;
    int d;
    if (*flag) d = (int)((const long long*)ei)[E + e];
    else       d = ((const int*)ei)[E + e];
    atomicAdd(&cnt[d], 1);
}

__global__ __launch_bounds__(256) void block_sums(const int* __restrict__ cnt,
                                                  int* __restrict__ bsum, int n) {
    __shared__ int sm[256];
    int i = blockIdx.x * 256 + threadIdx.x;
    sm[threadIdx.x] = (i < n) ? cnt[i] : 0;
    __syncthreads();
    for (int off = 128; off > 0; off >>= 1) {
        if (threadIdx.x < off) sm[threadIdx.x] += sm[threadIdx.x + off];
        __syncthreads();
    }
    if (threadIdx.x == 0) bsum[blockIdx.x] = sm[0];
}

__global__ __launch_bounds__(64) void scan_bsums(int* __restrict__ bsum, int nb) {
    int lane = threadIdx.x;
    int per = (nb + 63) / 64;
    int loc[8];
    int s = 0;
    for (int k = 0; k < per; ++k) {
        int v = (lane * per + k < nb) ? bsum[lane * per + k] : 0;
        loc[k] = s;
        s += v;
    }
    int incl = s;
    for (int off = 1; off < 64; off <<= 1) {
        int t = __shfl_up(incl, off);
        if (lane >= off) incl += t;
    }
    int ex = incl - s;
    for (int k = 0; k < per; ++k)
        if (lane * per + k < nb) bsum[lane * per + k] = ex + loc[k];
}

__global__ __launch_bounds__(256) void block_scan_apply(const int* __restrict__ cnt,
                                                        const int* __restrict__ bsum,
                                                        int* __restrict__ offs,
                                                        int* __restrict__ cursor, int n) {
    __shared__ int sm[256];
    int i = blockIdx.x * 256 + threadIdx.x;
    int v = (i < n) ? cnt[i] : 0;
    sm[threadIdx.x] = v;
    __syncthreads();
    for (int off = 1; off < 256; off <<= 1) {
        int t = (threadIdx.x >= off) ? sm[threadIdx.x - off] : 0;
        __syncthreads();
        sm[threadIdx.x] += t;
        __syncthreads();
    }
    int excl = bsum[blockIdx.x] + sm[threadIdx.x] - v;
    if (i < n) {
        offs[i] = excl;
        cursor[i] = excl;
    }
}

__global__ __launch_bounds__(256) void fill_csr(const void* __restrict__ ei,
                                                const int* __restrict__ flag,
                                                int* __restrict__ cursor,
                                                int* __restrict__ csr, int E) {
    int e = blockIdx.x * 256 + threadIdx.x;
    if (e >= E) return;
    int s, d;
    load_edge(ei, *flag, E, e, s, d);
    int pos = atomicAdd(&cursor[d], 1);
    csr[pos] = s;
}

// ---------------------------------------------------------------------------
// x (fp32 row-major) -> chunked bf16 [4][M][32]
// ---------------------------------------------------------------------------
__global__ __launch_bounds__(256) void convert_x(const float* __restrict__ x,
                                                 ushort* __restrict__ Xc, int M) {
    long long gid = (long long)blockIdx.x * 256 + threadIdx.x;
    if (gid >= (long long)M * 64) return;
    int node = (int)(gid >> 6), c2 = (int)(gid & 63);
    float2 v = *(const float2*)(x + (size_t)node * D + c2 * 2);
    int chunk = c2 >> 4;
    uint o = (uint)f2bf(v.x) | ((uint)f2bf(v.y) << 16);
    ((uint*)Xc)[(size_t)chunk * M * 16 + (size_t)node * 16 + (c2 & 15)] = o;
}

// ---------------------------------------------------------------------------
// Pack weights into MFMA B-fragment order:
// P[((ks*128 + n)*4 + g)*8 + j] = W[(ks*32+g*8+j)*128 + n]
// ---------------------------------------------------------------------------
__global__ __launch_bounds__(256) void pack_weights(const float* __restrict__ W0,
                                                    const float* __restrict__ W1,
                                                    const float* __restrict__ W2,
                                                    const float* __restrict__ W3,
                                                    ushort* __restrict__ P0,
                                                    ushort* __restrict__ P1,
                                                    ushort* __restrict__ P2,
                                                    ushort* __restrict__ P3) {
    int o = (blockIdx.x & 63) * 256 + threadIdx.x;  // 0..16383
    int which = blockIdx.x >> 6;
    const float* W = which == 0 ? W0 : which == 1 ? W1 : which == 2 ? W2 : W3;
    ushort* P = which == 0 ? P0 : which == 1 ? P1 : which == 2 ? P2 : P3;
    int j = o & 7, g = (o >> 3) & 3, n = (o >> 5) & 127, ks = o >> 12;
    int k = ks * 32 + g * 8 + j;
    P[o] = f2bf(W[k * 128 + n]);
}

// ---------------------------------------------------------------------------
// Chunked gather-aggregate with 16 edges in flight.
// Hc[c][i] = Xc[c][i] + sum_{j in in(i)} Xc[c][j]
// One wave per (node, chunk); 16 lanes x bf16x2 per edge, 4 edge-slots x
// unroll 4. Tail masked via clamp+select (no divergence).
// ---------------------------------------------------------------------------
__global__ __launch_bounds__(256) void aggregate_bf16(const ushort* __restrict__ Xc,
                                                      const int* __restrict__ offs,
                                                      const int* __restrict__ cnt,
                                                      const int* __restrict__ csr,
                                                      ushort* __restrict__ Hc, int M) {
    long long gid = (long long)blockIdx.x * 256 + threadIdx.x;
    int w = (int)(gid >> 6);
    if (w >= 4 * M) return;
    int lane = threadIdx.x & 63;
    int sub = lane >> 4, c16 = lane & 15;
    int chunk = w / M;
    int node = w - chunk * M;
    const uint* base = (const uint*)Xc + (size_t)chunk * M * 16;
    int beg = offs[node], deg = cnt[node];
    const int* ep = csr + beg;

    float ax = 0.f, ay = 0.f;
    for (int j0 = 0; j0 < deg; j0 += 16) {
        int es[4];
        uint us[4];
#pragma unroll
        for (int k = 0; k < 4; ++k) {
            int e = j0 + k * 4 + sub;
            es[k] = ep[e < deg ? e : 0];
        }
#pragma unroll
        for (int k = 0; k < 4; ++k) {
            uint u = base[(size_t)es[k] * 16 + c16];
            us[k] = (j0 + k * 4 + sub < deg) ? u : 0u;
        }
#pragma unroll
        for (int k = 0; k < 4; ++k) {
            ax += bf2f((ushort)(us[k] & 0xffff));
            ay += bf2f((ushort)(us[k] >> 16));
        }
    }
    ax += __shfl_xor(ax, 16); ay += __shfl_xor(ay, 16);
    ax += __shfl_xor(ax, 32); ay += __shfl_xor(ay, 32);
    uint su = base[(size_t)node * 16 + c16];
    ax += bf2f((ushort)(su & 0xffff));
    ay += bf2f((ushort)(su >> 16));
    if (sub == 0) {
        uint o = (uint)f2bf(ax) | ((uint)f2bf(ay) << 16);
        ((uint*)Hc)[(size_t)chunk * M * 16 + (size_t)node * 16 + c16] = o;
    }
}

// ---------------------------------------------------------------------------
// Fused MLP: C = relu(relu(A@Wa+ba)@Wb+bb)   (FINAL: out = sigmoid(C@Wfc+bfc),
// with C's relu applied before the dot, C not stored).
// A, C chunked bf16 [4][M][32]; Bpa/Bpb packed fragment-order weights.
// Intermediate 16x128 per-wave tile lives in XOR-swizzled LDS (unit ^ row):
// read-back ds_read_b128 is conflict-free (verified: 16 lanes -> 16 units).
// ---------------------------------------------------------------------------
template <int FINAL>
__global__ __launch_bounds__(256) void mlp_mfma(const ushort* __restrict__ A,
                                                const ushort* __restrict__ Bpa,
                                                const float* __restrict__ ba,
                                                const ushort* __restrict__ Bpb,
                                                const float* __restrict__ bb,
                                                const float* __restrict__ Wfc,
                                                const float* __restrict__ bfc,
                                                ushort* __restrict__ C,
                                                float* __restrict__ out, int M) {
    __shared__ ushort Hs[4][16][16][8];   // [wave][row][swz unit][j] = 16 KB
    int t = threadIdx.x;
    int wv = t >> 6, lane = t & 63;
    int l15 = lane & 15, g = lane >> 4;
    int row_base = blockIdx.x * 64 + wv * 16;
    int arow = row_base + l15;
    int arow_c = arow < M ? arow : M - 1;

    // ---- GEMM 1
    f32x4 acc[8];
#pragma unroll
    for (int i = 0; i < 8; ++i) acc[i] = (f32x4){0.f, 0.f, 0.f, 0.f};
#pragma unroll
    for (int ks = 0; ks < 4; ++ks) {
        short8 a = *(const short8*)(A + (size_t)ks * M * 32 + (size_t)arow_c * 32 + g * 8);
#pragma unroll
        for (int nt = 0; nt < 8; ++nt) {
            short8 b = *(const short8*)(Bpa + (((ks * 128 + nt * 16 + l15) * 4 + g) << 3));
            acc[nt] = __builtin_amdgcn_mfma_f32_16x16x32_bf16(a, b, acc[nt], 0, 0, 0);
        }
    }

    // ---- epilogue 1: relu -> swizzled LDS (wave-private 16x128 tile)
#pragma unroll
    for (int nt = 0; nt < 8; ++nt) {
        int col = nt * 16 + l15;
        float bv = ba[col];
        int u = col >> 3, j = col & 7;
#pragma unroll
        for (int r = 0; r < 4; ++r) {
            int row = g * 4 + r;
            float v = fmaxf(acc[nt][r] + bv, 0.f);
            Hs[wv][row][u ^ row][j] = f2bf(v);
        }
    }
    __syncthreads();

    // ---- GEMM 2
    f32x4 acc2[8];
#pragma unroll
    for (int i = 0; i < 8; ++i) acc2[i] = (f32x4){0.f, 0.f, 0.f, 0.f};
#pragma unroll
    for (int ks = 0; ks < 4; ++ks) {
        short8 a = *(const short8*)&Hs[wv][l15][(ks * 4 + g) ^ l15][0];
#pragma unroll
        for (int nt = 0; nt < 8; ++nt) {
            short8 b = *(const short8*)(Bpb + (((ks * 128 + nt * 16 + l15) * 4 + g) << 3));
            acc2[nt] = __builtin_amdgcn_mfma_f32_16x16x32_bf16(a, b, acc2[nt], 0, 0, 0);
        }
    }

    // ---- epilogue 2
    if (!FINAL) {
#pragma unroll
        for (int nt = 0; nt < 8; ++nt) {
            int col = nt * 16 + l15;
            float bv = bb[col];
            int chunk = col >> 5, cc = col & 31;
#pragma unroll
            for (int r = 0; r < 4; ++r) {
                int row = row_base + g * 4 + r;
                if (row < M) {
                    float v = fmaxf(acc2[nt][r] + bv, 0.f);
                    C[(size_t)chunk * M * 32 + (size_t)row * 32 + cc] = f2bf(v);
                }
            }
        }
    } else {
        float p[4] = {0.f, 0.f, 0.f, 0.f};
#pragma unroll
        for (int nt = 0; nt < 8; ++nt) {
            int col = nt * 16 + l15;
            float bv = bb[col];
            float wf = Wfc[col];
#pragma unroll
            for (int r = 0; r < 4; ++r) {
                float v = fmaxf(acc2[nt][r] + bv, 0.f);
                p[r] = fmaf(v, wf, p[r]);
            }
        }
#pragma unroll
        for (int r = 0; r < 4; ++r) {
            p[r] += __shfl_xor(p[r], 1);
            p[r] += __shfl_xor(p[r], 2);
            p[r] += __shfl_xor(p[r], 4);
            p[r] += __shfl_xor(p[r], 8);
        }
        if (l15 == 0) {
            float bf = bfc[0];
#pragma unroll
            for (int r = 0; r < 4; ++r) {
                int row = row_base + g * 4 + r;
                if (row < M) out[row] = 1.f / (1.f + expf(-(p[r] + bf)));
            }
        }
    }
}

extern "C" void kernel_launch(void* const* d_in, const int* in_sizes, int n_in,
                              void* d_out, int out_size, void* d_ws, size_t ws_size,
                              hipStream_t stream) {
    const float* x   = (const float*)d_in[0];
    const void*  ei  = d_in[1];
    const float* W1a = (const float*)d_in[2];
    const float* b1a = (const float*)d_in[3];
    const float* W1b = (const float*)d_in[4];
    const float* b1b = (const float*)d_in[5];
    const float* W2a = (const float*)d_in[6];
    const float* b2a = (const float*)d_in[7];
    const float* W2b = (const float*)d_in[8];
    const float* b2b = (const float*)d_in[9];
    const float* Wfc = (const float*)d_in[10];
    const float* bfc = (const float*)d_in[11];
    float* out = (float*)d_out;

    int M = in_sizes[0] / D;   // 50000
    int E = in_sizes[1] / 2;   // 800000
    size_t nf = (size_t)M * D;

    // workspace layout
    ushort* B0 = (ushort*)d_ws;          // chunked bf16 [4][M][32]
    ushort* B1 = B0 + nf;
    ushort* B2 = B1 + nf;
    ushort* P1a = B2 + nf;               // 4 x 16384 packed weights
    ushort* P1b = P1a + 16384;
    ushort* P2a = P1b + 16384;
    ushort* P2b = P2a + 16384;
    int* cnt    = (int*)(P2b + 16384);
    int* offs   = cnt + M;
    int* cursor = offs + M;
    int* csr    = cursor + M;
    int* flag   = csr + E;
    int nb = (M + 255) / 256;
    int* bsum   = flag + 1;

    int eBlocks = (E + 255) / 256;
    int mBlocks = (M + 255) / 256;
    int cvtBlocks = (int)(((long long)M * 64 + 255) / 256);
    int aggBlocks = (int)((4LL * M * 64 + 255) / 256);
    dim3 mlpGrid((M + 63) / 64);

    // ---- CSR build (once)
    zero_detect<<<mBlocks, 256, 0, stream>>>(cnt, M, (const unsigned int*)ei, flag);
    count_edges<<<eBlocks, 256, 0, stream>>>(ei, flag, cnt, E);
    block_sums<<<nb, 256, 0, stream>>>(cnt, bsum, M);
    scan_bsums<<<1, 64, 0, stream>>>(bsum, nb);
    block_scan_apply<<<nb, 256, 0, stream>>>(cnt, bsum, offs, cursor, M);
    fill_csr<<<eBlocks, 256, 0, stream>>>(ei, flag, cursor, csr, E);

    // ---- precompute bf16 inputs / packed weights
    convert_x<<<cvtBlocks, 256, 0, stream>>>(x, B0, M);
    pack_weights<<<256, 256, 0, stream>>>(W1a, W1b, W2a, W2b, P1a, P1b, P2a, P2b);

    // ---- layer 1
    aggregate_bf16<<<aggBlocks, 256, 0, stream>>>(B0, offs, cnt, csr, B1, M);
    mlp_mfma<0><<<mlpGrid, 256, 0, stream>>>(B1, P1a, b1a, P1b, b1b, nullptr, nullptr, B2, nullptr, M);

    // ---- layer 2
    aggregate_bf16<<<aggBlocks, 256, 0, stream>>>(B2, offs, cnt, csr, B0, M);
    mlp_mfma<1><<<mlpGrid, 256, 0, stream>>>(B0, P2a, b2a, P2b, b2b, Wfc, bfc, nullptr, out, M);
}

// Round 5
// 281.479 us; speedup vs baseline: 10.2244x; 1.0390x over previous
//
#include <hip/hip_runtime.h>
#include <hip/hip_fp16.h>
#include <cstdint>
#include <cstddef>

#define D 128
typedef __attribute__((ext_vector_type(8))) _Float16 half8;
typedef __attribute__((ext_vector_type(4))) float f32x4;

__device__ __forceinline__ uint pack2h(float x, float y) {
    __half2 h = __floats2half2_rn(x, y);
    return *(uint*)&h;
}
__device__ __forceinline__ __half2 u2h(uint u) { return *(__half2*)&u; }
__device__ __forceinline__ uint h2u(__half2 h) { return *(uint*)&h; }

// ---------------------------------------------------------------------------
// zero degree counters + edge dtype probe (int64 has odd dwords == 0)
// ---------------------------------------------------------------------------
__global__ __launch_bounds__(256) void zero_detect(int* __restrict__ cnt, int n,
                                                   const unsigned int* __restrict__ ei,
                                                   int* __restrict__ flag) {
    int i = blockIdx.x * 256 + threadIdx.x;
    if (i < n) cnt[i] = 0;
    if (i == 0) {
        int is64 = (ei[1] == 0u && ei[3] == 0u && ei[5] == 0u && ei[7] == 0u) ? 1 : 0;
        *flag = is64;
    }
}

__device__ __forceinline__ void load_edge(const void* ei, int flag, int E, int e,
                                          int& s, int& d) {
    if (flag) {
        const long long* e64 = (const long long*)ei;
        s = (int)e64[e];
        d = (int)e64[E + e];
    } else {
        const int* e32 = (const int*)ei;
        s = e32[e];
        d = e32[E + e];
    }
}

__global__ __launch_bounds__(256) void count_edges(const void* __restrict__ ei,
                                                   const int* __restrict__ flag,
                                                   int* __restrict__ cnt, int E) {
    int e = blockIdx.x * 256 + threadIdx.x;
    if (e >= E) return;
    int d;
    if (*flag) d = (int)((const long long*)ei)[E + e];
    else       d = ((const int*)ei)[E + e];
    atomicAdd(&cnt[d], 1);
}

__global__ __launch_bounds__(256) void block_sums(const int* __restrict__ cnt,
                                                  int* __restrict__ bsum, int n) {
    __shared__ int sm[256];
    int i = blockIdx.x * 256 + threadIdx.x;
    sm[threadIdx.x] = (i < n) ? cnt[i] : 0;
    __syncthreads();
    for (int off = 128; off > 0; off >>= 1) {
        if (threadIdx.x < off) sm[threadIdx.x] += sm[threadIdx.x + off];
        __syncthreads();
    }
    if (threadIdx.x == 0) bsum[blockIdx.x] = sm[0];
}

__global__ __launch_bounds__(64) void scan_bsums(int* __restrict__ bsum, int nb) {
    int lane = threadIdx.x;
    int per = (nb + 63) / 64;
    int loc[8];
    int s = 0;
    for (int k = 0; k < per; ++k) {
        int v = (lane * per + k < nb) ? bsum[lane * per + k] : 0;
        loc[k] = s;
        s += v;
    }
    int incl = s;
    for (int off = 1; off < 64; off <<= 1) {
        int t = __shfl_up(incl, off);
        if (lane >= off) incl += t;
    }
    int ex = incl - s;
    for (int k = 0; k < per; ++k)
        if (lane * per + k < nb) bsum[lane * per + k] = ex + loc[k];
}

__global__ __launch_bounds__(256) void block_scan_apply(const int* __restrict__ cnt,
                                                        const int* __restrict__ bsum,
                                                        int* __restrict__ offs,
                                                        int* __restrict__ cursor, int n) {
    __shared__ int sm[256];
    int i = blockIdx.x * 256 + threadIdx.x;
    int v = (i < n) ? cnt[i] : 0;
    sm[threadIdx.x] = v;
    __syncthreads();
    for (int off = 1; off < 256; off <<= 1) {
        int t = (threadIdx.x >= off) ? sm[threadIdx.x - off] : 0;
        __syncthreads();
        sm[threadIdx.x] += t;
        __syncthreads();
    }
    int excl = bsum[blockIdx.x] + sm[threadIdx.x] - v;
    if (i < n) {
        offs[i] = excl;
        cursor[i] = excl;
    }
}

__global__ __launch_bounds__(256) void fill_csr(const void* __restrict__ ei,
                                                const int* __restrict__ flag,
                                                int* __restrict__ cursor,
                                                int* __restrict__ csr, int E) {
    int e = blockIdx.x * 256 + threadIdx.x;
    if (e >= E) return;
    int s, d;
    load_edge(ei, *flag, E, e, s, d);
    int pos = atomicAdd(&cursor[d], 1);
    csr[pos] = s;
}

// ---------------------------------------------------------------------------
// x (fp32 row-major) -> chunked fp16 [4][M][32]
// ---------------------------------------------------------------------------
__global__ __launch_bounds__(256) void convert_x(const float* __restrict__ x,
                                                 ushort* __restrict__ Xc, int M) {
    long long gid = (long long)blockIdx.x * 256 + threadIdx.x;
    if (gid >= (long long)M * 64) return;
    int node = (int)(gid >> 6), c2 = (int)(gid & 63);
    float2 v = *(const float2*)(x + (size_t)node * D + c2 * 2);
    int chunk = c2 >> 4;
    ((uint*)Xc)[(size_t)chunk * M * 16 + (size_t)node * 16 + (c2 & 15)] = pack2h(v.x, v.y);
}

// ---------------------------------------------------------------------------
// Pack weights (fp32 [128][128]) into fp16 MFMA B-fragment order:
// P[((ks*128 + n)*4 + g)*8 + j] = W[(ks*32+g*8+j)*128 + n]
// ---------------------------------------------------------------------------
__global__ __launch_bounds__(256) void pack_weights(const float* __restrict__ W0,
                                                    const float* __restrict__ W1,
                                                    const float* __restrict__ W2,
                                                    const float* __restrict__ W3,
                                                    ushort* __restrict__ P0,
                                                    ushort* __restrict__ P1,
                                                    ushort* __restrict__ P2,
                                                    ushort* __restrict__ P3) {
    int o = (blockIdx.x & 63) * 256 + threadIdx.x;  // 0..16383
    int which = blockIdx.x >> 6;
    const float* W = which == 0 ? W0 : which == 1 ? W1 : which == 2 ? W2 : W3;
    ushort* P = which == 0 ? P0 : which == 1 ? P1 : which == 2 ? P2 : P3;
    int j = o & 7, g = (o >> 3) & 3, n = (o >> 5) & 127, ks = o >> 12;
    int k = ks * 32 + g * 8 + j;
    __half h = __float2half_rn(W[k * 128 + n]);
    P[o] = *(ushort*)&h;
}

// ---------------------------------------------------------------------------
// Chunked gather-aggregate, fp16 packed adds, 16 edges in flight.
// Hc[c][i] = Xc[c][i] + sum_{j in in(i)} Xc[c][j]
// Block->XCD partitioning: chunk c only on XCD slots {2c, 2c+1} (b&7 = 2c+s),
// so each 3.2 MB chunk is replicated into at most 2 XCD L2s instead of 8.
// ---------------------------------------------------------------------------
__global__ __launch_bounds__(256) void aggregate_f16(const ushort* __restrict__ Xc,
                                                     const int* __restrict__ offs,
                                                     const int* __restrict__ cnt,
                                                     const int* __restrict__ csr,
                                                     ushort* __restrict__ Hc, int M) {
    int b = blockIdx.x;
    int chunk = (b & 7) >> 1;
    int ng = (b >> 3) * 2 + (b & 1);
    int wv = threadIdx.x >> 6;
    int node = ng * 4 + wv;
    if (node >= M) return;
    int lane = threadIdx.x & 63;
    int sub = lane >> 4, c16 = lane & 15;
    const uint* base = (const uint*)Xc + (size_t)chunk * M * 16;
    int beg = offs[node], deg = cnt[node];
    const int* ep = csr + beg;

    uint au[4] = {0u, 0u, 0u, 0u};
    for (int j0 = 0; j0 < deg; j0 += 16) {
        int es[4];
        uint us[4];
#pragma unroll
        for (int k = 0; k < 4; ++k) {
            int e = j0 + k * 4 + sub;
            es[k] = ep[e < deg ? e : 0];
        }
#pragma unroll
        for (int k = 0; k < 4; ++k) {
            uint u = base[(size_t)es[k] * 16 + c16];
            us[k] = (j0 + k * 4 + sub < deg) ? u : 0u;
        }
#pragma unroll
        for (int k = 0; k < 4; ++k) {
            __half2 a = __hadd2(u2h(au[k]), u2h(us[k]));
            au[k] = h2u(a);
        }
    }
    __half2 a01 = __hadd2(u2h(au[0]), u2h(au[1]));
    __half2 a23 = __hadd2(u2h(au[2]), u2h(au[3]));
    __half2 a = __hadd2(a01, a23);
    uint t = (uint)__shfl_xor((int)h2u(a), 16);
    a = __hadd2(a, u2h(t));
    t = (uint)__shfl_xor((int)h2u(a), 32);
    a = __hadd2(a, u2h(t));
    a = __hadd2(a, u2h(base[(size_t)node * 16 + c16]));   // self term
    if (sub == 0)
        ((uint*)Hc)[(size_t)chunk * M * 16 + (size_t)node * 16 + c16] = h2u(a);
}

// ---------------------------------------------------------------------------
// Fused MLP: C = relu(relu(A@Wa+ba)@Wb+bb)  (FINAL: out = sigmoid(C@Wfc+bfc)).
// A, C chunked fp16 [4][M][32]; Bpa/Bpb packed fragment-order fp16 weights.
// B fragments staged in LDS (32 KB buffer reused for Wb); A fragments
// prefetched to registers before staging so global latency is hidden.
// Intermediate 16x128 tile in XOR-swizzled LDS (conflict-free b128 readback).
// ---------------------------------------------------------------------------
template <int FINAL>
__global__ __launch_bounds__(256) void mlp_mfma(const ushort* __restrict__ A,
                                                const ushort* __restrict__ Bpa,
                                                const float* __restrict__ ba,
                                                const ushort* __restrict__ Bpb,
                                                const float* __restrict__ bb,
                                                const float* __restrict__ Wfc,
                                                const float* __restrict__ bfc,
                                                ushort* __restrict__ C,
                                                float* __restrict__ out, int M) {
    __shared__ ushort sB[16384];           // 32 KB: current packed weight matrix
    __shared__ ushort Hs[4][16][16][8];    // 16 KB: per-wave 16x128 intermediate
    int t = threadIdx.x;
    int wv = t >> 6, lane = t & 63;
    int l15 = lane & 15, g = lane >> 4;
    int row_base = blockIdx.x * 64 + wv * 16;
    int arow = row_base + l15;
    int arow_c = arow < M ? arow : M - 1;

    // prefetch A fragments (global latency hides under B staging + barrier)
    half8 a_frag[4];
#pragma unroll
    for (int ks = 0; ks < 4; ++ks)
        a_frag[ks] = *(const half8*)(A + (size_t)ks * M * 32 + (size_t)arow_c * 32 + g * 8);

    // stage Wa fragments
    for (int i = t; i < 2048; i += 256) ((uint4*)sB)[i] = ((const uint4*)Bpa)[i];
    __syncthreads();

    // ---- GEMM 1
    f32x4 acc[8];
#pragma unroll
    for (int i = 0; i < 8; ++i) acc[i] = (f32x4){0.f, 0.f, 0.f, 0.f};
#pragma unroll
    for (int ks = 0; ks < 4; ++ks) {
#pragma unroll
        for (int nt = 0; nt < 8; ++nt) {
            half8 b = *(const half8*)&sB[((ks * 128 + nt * 16 + l15) * 4 + g) << 3];
            acc[nt] = __builtin_amdgcn_mfma_f32_16x16x32_f16(a_frag[ks], b, acc[nt], 0, 0, 0);
        }
    }

    // ---- epilogue 1: relu -> swizzled LDS
#pragma unroll
    for (int nt = 0; nt < 8; ++nt) {
        int col = nt * 16 + l15;
        float bv = ba[col];
        int u = col >> 3, j = col & 7;
#pragma unroll
        for (int r = 0; r < 4; ++r) {
            int row = g * 4 + r;
            float v = fmaxf(acc[nt][r] + bv, 0.f);
            __half h = __float2half_rn(v);
            Hs[wv][row][u ^ row][j] = *(ushort*)&h;
        }
    }
    __syncthreads();

    // stage Wb fragments (sB reuse; all waves done reading Wa)
    for (int i = t; i < 2048; i += 256) ((uint4*)sB)[i] = ((const uint4*)Bpb)[i];
    __syncthreads();

    // ---- GEMM 2
    f32x4 acc2[8];
#pragma unroll
    for (int i = 0; i < 8; ++i) acc2[i] = (f32x4){0.f, 0.f, 0.f, 0.f};
#pragma unroll
    for (int ks = 0; ks < 4; ++ks) {
        half8 a = *(const half8*)&Hs[wv][l15][(ks * 4 + g) ^ l15][0];
#pragma unroll
        for (int nt = 0; nt < 8; ++nt) {
            half8 b = *(const half8*)&sB[((ks * 128 + nt * 16 + l15) * 4 + g) << 3];
            acc2[nt] = __builtin_amdgcn_mfma_f32_16x16x32_f16(a, b, acc2[nt], 0, 0, 0);
        }
    }

    // ---- epilogue 2
    if (!FINAL) {
#pragma unroll
        for (int nt = 0; nt < 8; ++nt) {
            int col = nt * 16 + l15;
            float bv = bb[col];
            int chunk = col >> 5, cc = col & 31;
#pragma unroll
            for (int r = 0; r < 4; ++r) {
                int row = row_base + g * 4 + r;
                if (row < M) {
                    float v = fmaxf(acc2[nt][r] + bv, 0.f);
                    __half h = __float2half_rn(v);
                    C[(size_t)chunk * M * 32 + (size_t)row * 32 + cc] = *(ushort*)&h;
                }
            }
        }
    } else {
        float p[4] = {0.f, 0.f, 0.f, 0.f};
#pragma unroll
        for (int nt = 0; nt < 8; ++nt) {
            int col = nt * 16 + l15;
            float bv = bb[col];
            float wf = Wfc[col];
#pragma unroll
            for (int r = 0; r < 4; ++r) {
                float v = fmaxf(acc2[nt][r] + bv, 0.f);
                p[r] = fmaf(v, wf, p[r]);
            }
        }
#pragma unroll
        for (int r = 0; r < 4; ++r) {
            p[r] += __shfl_xor(p[r], 1);
            p[r] += __shfl_xor(p[r], 2);
            p[r] += __shfl_xor(p[r], 4);
            p[r] += __shfl_xor(p[r], 8);
        }
        if (l15 == 0) {
            float bf = bfc[0];
#pragma unroll
            for (int r = 0; r < 4; ++r) {
                int row = row_base + g * 4 + r;
                if (row < M) out[row] = 1.f / (1.f + expf(-(p[r] + bf)));
            }
        }
    }
}

extern "C" void kernel_launch(void* const* d_in, const int* in_sizes, int n_in,
                              void* d_out, int out_size, void* d_ws, size_t ws_size,
                              hipStream_t stream) {
    const float* x   = (const float*)d_in[0];
    const void*  ei  = d_in[1];
    const float* W1a = (const float*)d_in[2];
    const float* b1a = (const float*)d_in[3];
    const float* W1b = (const float*)d_in[4];
    const float* b1b = (const float*)d_in[5];
    const float* W2a = (const float*)d_in[6];
    const float* b2a = (const float*)d_in[7];
    const float* W2b = (const float*)d_in[8];
    const float* b2b = (const float*)d_in[9];
    const float* Wfc = (const float*)d_in[10];
    const float* bfc = (const float*)d_in[11];
    float* out = (float*)d_out;

    int M = in_sizes[0] / D;   // 50000
    int E = in_sizes[1] / 2;   // 800000
    size_t nf = (size_t)M * D;

    // workspace layout
    ushort* B0 = (ushort*)d_ws;          // chunked fp16 [4][M][32]
    ushort* B1 = B0 + nf;
    ushort* B2 = B1 + nf;
    ushort* P1a = B2 + nf;               // 4 x 16384 packed weights
    ushort* P1b = P1a + 16384;
    ushort* P2a = P1b + 16384;
    ushort* P2b = P2a + 16384;
    int* cnt    = (int*)(P2b + 16384);
    int* offs   = cnt + M;
    int* cursor = offs + M;
    int* csr    = cursor + M;
    int* flag   = csr + E;
    int nb = (M + 255) / 256;
    int* bsum   = flag + 1;

    int eBlocks = (E + 255) / 256;
    int mBlocks = (M + 255) / 256;
    int cvtBlocks = (int)(((long long)M * 64 + 255) / 256);
    int npb = (M + 3) / 4;                         // node-groups per chunk
    int aggBlocks = ((npb * 4 + 7) / 8) * 8;       // XCD-slot-aligned grid
    dim3 mlpGrid((M + 63) / 64);

    // ---- CSR build (once)
    zero_detect<<<mBlocks, 256, 0, stream>>>(cnt, M, (const unsigned int*)ei, flag);
    count_edges<<<eBlocks, 256, 0, stream>>>(ei, flag, cnt, E);
    block_sums<<<nb, 256, 0, stream>>>(cnt, bsum, M);
    scan_bsums<<<1, 64, 0, stream>>>(bsum, nb);
    block_scan_apply<<<nb, 256, 0, stream>>>(cnt, bsum, offs, cursor, M);
    fill_csr<<<eBlocks, 256, 0, stream>>>(ei, flag, cursor, csr, E);

    // ---- precompute fp16 inputs / packed weights
    convert_x<<<cvtBlocks, 256, 0, stream>>>(x, B0, M);
    pack_weights<<<256, 256, 0, stream>>>(W1a, W1b, W2a, W2b, P1a, P1b, P2a, P2b);

    // ---- layer 1
    aggregate_f16<<<aggBlocks, 256, 0, stream>>>(B0, offs, cnt, csr, B1, M);
    mlp_mfma<0><<<mlpGrid, 256, 0, stream>>>(B1, P1a, b1a, P1b, b1b, nullptr, nullptr, B2, nullptr, M);

    // ---- layer 2
    aggregate_f16<<<aggBlocks, 256, 0, stream>>>(B2, offs, cnt, csr, B0, M);
    mlp_mfma<1><<<mlpGrid, 256, 0, stream>>>(B0, P2a, b2a, P2b, b2b, Wfc, bfc, nullptr, out, M);
}

// Round 6
// 236.955 us; speedup vs baseline: 12.1456x; 1.1879x over previous
//
#include <hip/hip_runtime.h>
#include <hip/hip_fp16.h>
#include <cstdint>
#include <cstddef>

#define D 128
typedef __attribute__((ext_vector_type(8))) _Float16 half8;
typedef __attribute__((ext_vector_type(4))) float f32x4;

__device__ __forceinline__ uint pack2h(float x, float y) {
    __half2 h = __floats2half2_rn(x, y);
    return *(uint*)&h;
}
__device__ __forceinline__ __half2 u2h(uint u) { return *(__half2*)&u; }
__device__ __forceinline__ uint h2u(__half2 h) { return *(uint*)&h; }

// ---------------------------------------------------------------------------
// zero degree counters + edge dtype probe (int64 has odd dwords == 0)
// ---------------------------------------------------------------------------
__global__ __launch_bounds__(256) void zero_detect(int* __restrict__ cnt, int n,
                                                   const unsigned int* __restrict__ ei,
                                                   int* __restrict__ flag) {
    int i = blockIdx.x * 256 + threadIdx.x;
    if (i < n) cnt[i] = 0;
    if (i == 0) {
        int is64 = (ei[1] == 0u && ei[3] == 0u && ei[5] == 0u && ei[7] == 0u) ? 1 : 0;
        *flag = is64;
    }
}

__device__ __forceinline__ void load_edge(const void* ei, int flag, int E, int e,
                                          int& s, int& d) {
    if (flag) {
        const long long* e64 = (const long long*)ei;
        s = (int)e64[e];
        d = (int)e64[E + e];
    } else {
        const int* e32 = (const int*)ei;
        s = e32[e];
        d = e32[E + e];
    }
}

__global__ __launch_bounds__(256) void count_edges(const void* __restrict__ ei,
                                                   const int* __restrict__ flag,
                                                   int* __restrict__ cnt, int E) {
    int e = blockIdx.x * 256 + threadIdx.x;
    if (e >= E) return;
    int d;
    if (*flag) d = (int)((const long long*)ei)[E + e];
    else       d = ((const int*)ei)[E + e];
    atomicAdd(&cnt[d], 1);
}

__global__ __launch_bounds__(256) void block_sums(const int* __restrict__ cnt,
                                                  int* __restrict__ bsum, int n) {
    __shared__ int sm[256];
    int i = blockIdx.x * 256 + threadIdx.x;
    sm[threadIdx.x] = (i < n) ? cnt[i] : 0;
    __syncthreads();
    for (int off = 128; off > 0; off >>= 1) {
        if (threadIdx.x < off) sm[threadIdx.x] += sm[threadIdx.x + off];
        __syncthreads();
    }
    if (threadIdx.x == 0) bsum[blockIdx.x] = sm[0];
}

__global__ __launch_bounds__(64) void scan_bsums(int* __restrict__ bsum, int nb) {
    int lane = threadIdx.x;
    int per = (nb + 63) / 64;
    int loc[8];
    int s = 0;
    for (int k = 0; k < per; ++k) {
        int v = (lane * per + k < nb) ? bsum[lane * per + k] : 0;
        loc[k] = s;
        s += v;
    }
    int incl = s;
    for (int off = 1; off < 64; off <<= 1) {
        int t = __shfl_up(incl, off);
        if (lane >= off) incl += t;
    }
    int ex = incl - s;
    for (int k = 0; k < per; ++k)
        if (lane * per + k < nb) bsum[lane * per + k] = ex + loc[k];
}

__global__ __launch_bounds__(256) void block_scan_apply(const int* __restrict__ cnt,
                                                        const int* __restrict__ bsum,
                                                        int* __restrict__ offs,
                                                        int* __restrict__ cursor, int n) {
    __shared__ int sm[256];
    int i = blockIdx.x * 256 + threadIdx.x;
    int v = (i < n) ? cnt[i] : 0;
    sm[threadIdx.x] = v;
    __syncthreads();
    for (int off = 1; off < 256; off <<= 1) {
        int t = (threadIdx.x >= off) ? sm[threadIdx.x - off] : 0;
        __syncthreads();
        sm[threadIdx.x] += t;
        __syncthreads();
    }
    int excl = bsum[blockIdx.x] + sm[threadIdx.x] - v;
    if (i < n) {
        offs[i] = excl;
        cursor[i] = excl;
    }
}

__global__ __launch_bounds__(256) void fill_csr(const void* __restrict__ ei,
                                                const int* __restrict__ flag,
                                                int* __restrict__ cursor,
                                                int* __restrict__ csr, int E) {
    int e = blockIdx.x * 256 + threadIdx.x;
    if (e >= E) return;
    int s, d;
    load_edge(ei, *flag, E, e, s, d);
    int pos = atomicAdd(&cursor[d], 1);
    csr[pos] = s;
}

// ---------------------------------------------------------------------------
// x (fp32 row-major) -> chunked fp16 [4][M][32]
// ---------------------------------------------------------------------------
__global__ __launch_bounds__(256) void convert_x(const float* __restrict__ x,
                                                 ushort* __restrict__ Xc, int M) {
    long long gid = (long long)blockIdx.x * 256 + threadIdx.x;
    if (gid >= (long long)M * 64) return;
    int node = (int)(gid >> 6), c2 = (int)(gid & 63);
    float2 v = *(const float2*)(x + (size_t)node * D + c2 * 2);
    int chunk = c2 >> 4;
    ((uint*)Xc)[(size_t)chunk * M * 16 + (size_t)node * 16 + (c2 & 15)] = pack2h(v.x, v.y);
}

// ---------------------------------------------------------------------------
// Pack weights (fp32 [128][128]) into fp16 MFMA B-fragment order:
// P[((ks*128 + n)*4 + g)*8 + j] = W[(ks*32+g*8+j)*128 + n]
// ---------------------------------------------------------------------------
__global__ __launch_bounds__(256) void pack_weights(const float* __restrict__ W0,
                                                    const float* __restrict__ W1,
                                                    const float* __restrict__ W2,
                                                    const float* __restrict__ W3,
                                                    ushort* __restrict__ P0,
                                                    ushort* __restrict__ P1,
                                                    ushort* __restrict__ P2,
                                                    ushort* __restrict__ P3) {
    int o = (blockIdx.x & 63) * 256 + threadIdx.x;  // 0..16383
    int which = blockIdx.x >> 6;
    const float* W = which == 0 ? W0 : which == 1 ? W1 : which == 2 ? W2 : W3;
    ushort* P = which == 0 ? P0 : which == 1 ? P1 : which == 2 ? P2 : P3;
    int j = o & 7, g = (o >> 3) & 3, n = (o >> 5) & 127, ks = o >> 12;
    int k = ks * 32 + g * 8 + j;
    __half h = __float2half_rn(W[k * 128 + n]);
    P[o] = *(ushort*)&h;
}

// ---------------------------------------------------------------------------
// Gather-aggregate, one wave per NODE (all 4 chunks at once).
// Lane = (chunk = lane>>4, col = lane&15); an edge's full 256B row is loaded
// by the whole wave in one instruction. node + all edge indices are
// wave-uniform scalars -> offs/cnt/csr go through s_load on the SMEM pipe,
// gathers are SGPR-base + constant-VGPR-offset, and no cross-lane reduction
// is needed (each lane owns its output element). 8 edges in flight.
// ---------------------------------------------------------------------------
__global__ __launch_bounds__(256) void aggregate_f16(const ushort* __restrict__ Xc,
                                                     const int* __restrict__ offs,
                                                     const int* __restrict__ cnt,
                                                     const int* __restrict__ csr,
                                                     ushort* __restrict__ Hc, int M) {
    int wv = __builtin_amdgcn_readfirstlane((int)(threadIdx.x >> 6));
    int node = blockIdx.x * 4 + wv;
    if (node >= M) return;
    int lane = threadIdx.x & 63;
    int chunk = lane >> 4, c16 = lane & 15;
    int vo = chunk * (M * 16) + c16;              // lane-constant element offset
    const uint* X = (const uint*)Xc;

    int beg = offs[node], deg = cnt[node];
    const int* ep = csr + beg;

    __half2 acc = u2h(X[(size_t)node * 16 + vo]);   // self term
    for (int j0 = 0; j0 < deg; j0 += 8) {
        int es[8];
        uint us[8];
#pragma unroll
        for (int k = 0; k < 8; ++k) {
            int e = j0 + k;
            es[k] = ep[e < deg ? e : 0];            // scalar loads (uniform)
        }
#pragma unroll
        for (int k = 0; k < 8; ++k)
            us[k] = X[(size_t)es[k] * 16 + vo];     // wave-wide 256B row gather
#pragma unroll
        for (int k = 0; k < 8; ++k)
            us[k] = (j0 + k < deg) ? us[k] : 0u;
        __half2 s0 = __hadd2(u2h(us[0]), u2h(us[1]));
        __half2 s1 = __hadd2(u2h(us[2]), u2h(us[3]));
        __half2 s2 = __hadd2(u2h(us[4]), u2h(us[5]));
        __half2 s3 = __hadd2(u2h(us[6]), u2h(us[7]));
        s0 = __hadd2(s0, s1);
        s2 = __hadd2(s2, s3);
        acc = __hadd2(acc, __hadd2(s0, s2));
    }
    ((uint*)Hc)[(size_t)node * 16 + vo] = h2u(acc);
}

// ---------------------------------------------------------------------------
// Fused MLP: C = relu(relu(A@Wa+ba)@Wb+bb)  (FINAL: out = sigmoid(C@Wfc+bfc)).
// A, C chunked fp16 [4][M][32]; Bpa/Bpb packed fragment-order fp16 weights.
// B fragments staged in LDS (32 KB buffer reused for Wb); A fragments
// prefetched to registers before staging so global latency is hidden.
// Intermediate 16x128 tile in XOR-swizzled LDS (conflict-free b128 readback).
// ---------------------------------------------------------------------------
template <int FINAL>
__global__ __launch_bounds__(256) void mlp_mfma(const ushort* __restrict__ A,
                                                const ushort* __restrict__ Bpa,
                                                const float* __restrict__ ba,
                                                const ushort* __restrict__ Bpb,
                                                const float* __restrict__ bb,
                                                const float* __restrict__ Wfc,
                                                const float* __restrict__ bfc,
                                                ushort* __restrict__ C,
                                                float* __restrict__ out, int M) {
    __shared__ ushort sB[16384];           // 32 KB: current packed weight matrix
    __shared__ ushort Hs[4][16][16][8];    // 16 KB: per-wave 16x128 intermediate
    int t = threadIdx.x;
    int wv = t >> 6, lane = t & 63;
    int l15 = lane & 15, g = lane >> 4;
    int row_base = blockIdx.x * 64 + wv * 16;
    int arow = row_base + l15;
    int arow_c = arow < M ? arow : M - 1;

    // prefetch A fragments (global latency hides under B staging + barrier)
    half8 a_frag[4];
#pragma unroll
    for (int ks = 0; ks < 4; ++ks)
        a_frag[ks] = *(const half8*)(A + (size_t)ks * M * 32 + (size_t)arow_c * 32 + g * 8);

    // stage Wa fragments
    for (int i = t; i < 2048; i += 256) ((uint4*)sB)[i] = ((const uint4*)Bpa)[i];
    __syncthreads();

    // ---- GEMM 1
    f32x4 acc[8];
#pragma unroll
    for (int i = 0; i < 8; ++i) acc[i] = (f32x4){0.f, 0.f, 0.f, 0.f};
#pragma unroll
    for (int ks = 0; ks < 4; ++ks) {
#pragma unroll
        for (int nt = 0; nt < 8; ++nt) {
            half8 b = *(const half8*)&sB[((ks * 128 + nt * 16 + l15) * 4 + g) << 3];
            acc[nt] = __builtin_amdgcn_mfma_f32_16x16x32_f16(a_frag[ks], b, acc[nt], 0, 0, 0);
        }
    }

    // ---- epilogue 1: relu -> swizzled LDS
#pragma unroll
    for (int nt = 0; nt < 8; ++nt) {
        int col = nt * 16 + l15;
        float bv = ba[col];
        int u = col >> 3, j = col & 7;
#pragma unroll
        for (int r = 0; r < 4; ++r) {
            int row = g * 4 + r;
            float v = fmaxf(acc[nt][r] + bv, 0.f);
            __half h = __float2half_rn(v);
            Hs[wv][row][u ^ row][j] = *(ushort*)&h;
        }
    }
    __syncthreads();

    // stage Wb fragments (sB reuse; all waves done reading Wa)
    for (int i = t; i < 2048; i += 256) ((uint4*)sB)[i] = ((const uint4*)Bpb)[i];
    __syncthreads();

    // ---- GEMM 2
    f32x4 acc2[8];
#pragma unroll
    for (int i = 0; i < 8; ++i) acc2[i] = (f32x4){0.f, 0.f, 0.f, 0.f};
#pragma unroll
    for (int ks = 0; ks < 4; ++ks) {
        half8 a = *(const half8*)&Hs[wv][l15][(ks * 4 + g) ^ l15][0];
#pragma unroll
        for (int nt = 0; nt < 8; ++nt) {
            half8 b = *(const half8*)&sB[((ks * 128 + nt * 16 + l15) * 4 + g) << 3];
            acc2[nt] = __builtin_amdgcn_mfma_f32_16x16x32_f16(a, b, acc2[nt], 0, 0, 0);
        }
    }

    // ---- epilogue 2
    if (!FINAL) {
#pragma unroll
        for (int nt = 0; nt < 8; ++nt) {
            int col = nt * 16 + l15;
            float bv = bb[col];
            int chunk = col >> 5, cc = col & 31;
#pragma unroll
            for (int r = 0; r < 4; ++r) {
                int row = row_base + g * 4 + r;
                if (row < M) {
                    float v = fmaxf(acc2[nt][r] + bv, 0.f);
                    __half h = __float2half_rn(v);
                    C[(size_t)chunk * M * 32 + (size_t)row * 32 + cc] = *(ushort*)&h;
                }
            }
        }
    } else {
        float p[4] = {0.f, 0.f, 0.f, 0.f};
#pragma unroll
        for (int nt = 0; nt < 8; ++nt) {
            int col = nt * 16 + l15;
            float bv = bb[col];
            float wf = Wfc[col];
#pragma unroll
            for (int r = 0; r < 4; ++r) {
                float v = fmaxf(acc2[nt][r] + bv, 0.f);
                p[r] = fmaf(v, wf, p[r]);
            }
        }
#pragma unroll
        for (int r = 0; r < 4; ++r) {
            p[r] += __shfl_xor(p[r], 1);
            p[r] += __shfl_xor(p[r], 2);
            p[r] += __shfl_xor(p[r], 4);
            p[r] += __shfl_xor(p[r], 8);
        }
        if (l15 == 0) {
            float bf = bfc[0];
#pragma unroll
            for (int r = 0; r < 4; ++r) {
                int row = row_base + g * 4 + r;
                if (row < M) out[row] = 1.f / (1.f + expf(-(p[r] + bf)));
            }
        }
    }
}

extern "C" void kernel_launch(void* const* d_in, const int* in_sizes, int n_in,
                              void* d_out, int out_size, void* d_ws, size_t ws_size,
                              hipStream_t stream) {
    const float* x   = (const float*)d_in[0];
    const void*  ei  = d_in[1];
    const float* W1a = (const float*)d_in[2];
    const float* b1a = (const float*)d_in[3];
    const float* W1b = (const float*)d_in[4];
    const float* b1b = (const float*)d_in[5];
    const float* W2a = (const float*)d_in[6];
    const float* b2a = (const float*)d_in[7];
    const float* W2b = (const float*)d_in[8];
    const float* b2b = (const float*)d_in[9];
    const float* Wfc = (const float*)d_in[10];
    const float* bfc = (const float*)d_in[11];
    float* out = (float*)d_out;

    int M = in_sizes[0] / D;   // 50000
    int E = in_sizes[1] / 2;   // 800000
    size_t nf = (size_t)M * D;

    // workspace layout
    ushort* B0 = (ushort*)d_ws;          // chunked fp16 [4][M][32]
    ushort* B1 = B0 + nf;
    ushort* B2 = B1 + nf;
    ushort* P1a = B2 + nf;               // 4 x 16384 packed weights
    ushort* P1b = P1a + 16384;
    ushort* P2a = P1b + 16384;
    ushort* P2b = P2a + 16384;
    int* cnt    = (int*)(P2b + 16384);
    int* offs   = cnt + M;
    int* cursor = offs + M;
    int* csr    = cursor + M;
    int* flag   = csr + E;
    int nb = (M + 255) / 256;
    int* bsum   = flag + 1;

    int eBlocks = (E + 255) / 256;
    int mBlocks = (M + 255) / 256;
    int cvtBlocks = (int)(((long long)M * 64 + 255) / 256);
    int aggBlocks = (M + 3) / 4;
    dim3 mlpGrid((M + 63) / 64);

    // ---- CSR build (once)
    zero_detect<<<mBlocks, 256, 0, stream>>>(cnt, M, (const unsigned int*)ei, flag);
    count_edges<<<eBlocks, 256, 0, stream>>>(ei, flag, cnt, E);
    block_sums<<<nb, 256, 0, stream>>>(cnt, bsum, M);
    scan_bsums<<<1, 64, 0, stream>>>(bsum, nb);
    block_scan_apply<<<nb, 256, 0, stream>>>(cnt, bsum, offs, cursor, M);
    fill_csr<<<eBlocks, 256, 0, stream>>>(ei, flag, cursor, csr, E);

    // ---- precompute fp16 inputs / packed weights
    convert_x<<<cvtBlocks, 256, 0, stream>>>(x, B0, M);
    pack_weights<<<256, 256, 0, stream>>>(W1a, W1b, W2a, W2b, P1a, P1b, P2a, P2b);

    // ---- layer 1
    aggregate_f16<<<aggBlocks, 256, 0, stream>>>(B0, offs, cnt, csr, B1, M);
    mlp_mfma<0><<<mlpGrid, 256, 0, stream>>>(B1, P1a, b1a, P1b, b1b, nullptr, nullptr, B2, nullptr, M);

    // ---- layer 2
    aggregate_f16<<<aggBlocks, 256, 0, stream>>>(B2, offs, cnt, csr, B0, M);
    mlp_mfma<1><<<mlpGrid, 256, 0, stream>>>(B0, P2a, b2a, P2b, b2b, Wfc, bfc, nullptr, out, M);
}

// Round 7
// 220.871 us; speedup vs baseline: 13.0300x; 1.0728x over previous
//
#include <hip/hip_runtime.h>
#include <hip/hip_fp16.h>
#include <cstdint>
#include <cstddef>

#define D 128
#define NP 8   // dst partitions == XCD count
typedef __attribute__((ext_vector_type(8))) _Float16 half8;
typedef __attribute__((ext_vector_type(4))) float f32x4;

__device__ __forceinline__ uint pack2h(float x, float y) {
    __half2 h = __floats2half2_rn(x, y);
    return *(uint*)&h;
}
__device__ __forceinline__ __half2 u2h(uint u) { return *(__half2*)&u; }
__device__ __forceinline__ uint h2u(__half2 h) { return *(uint*)&h; }

// ---------------------------------------------------------------------------
// zero degree counters + edge dtype probe (int64 has odd dwords == 0)
// ---------------------------------------------------------------------------
__global__ __launch_bounds__(256) void zero_detect(int* __restrict__ cnt, int n,
                                                   const unsigned int* __restrict__ ei,
                                                   int* __restrict__ flag) {
    int i = blockIdx.x * 256 + threadIdx.x;
    if (i < n) cnt[i] = 0;
    if (i == 0) {
        int is64 = (ei[1] == 0u && ei[3] == 0u && ei[5] == 0u && ei[7] == 0u) ? 1 : 0;
        *flag = is64;
    }
}

// ---------------------------------------------------------------------------
// Partitioned CSR build. blockIdx&7 = dst partition; round-robin dispatch pins
// each partition to one XCD, so cnt/cursor atomics and csr writes stay in that
// XCD's L2 (no cross-XCD line ping-pong). Each partition re-scans the edge
// plane (L3-resident). sh = 1 for int64 edges (read low dword at 2*e).
// ---------------------------------------------------------------------------
__global__ __launch_bounds__(256) void count_edges_part(const void* __restrict__ ei,
                                                        const int* __restrict__ flag,
                                                        int* __restrict__ cnt,
                                                        int E, int M, int nslice) {
    int p = blockIdx.x & (NP - 1);
    int slice = blockIdx.x >> 3;
    int psz = (M + NP - 1) / NP;
    int lo = p * psz, hi = min(M, lo + psz);
    int eps = (E + nslice - 1) / nslice;
    int e0 = slice * eps, e1 = min(E, e0 + eps);
    int sh = *flag;
    const int* dp = (const int*)ei + ((long long)E << sh);
    for (int e = e0 + threadIdx.x; e < e1; e += 256) {
        int d = dp[e << sh];
        if (d >= lo && d < hi) atomicAdd(&cnt[d], 1);
    }
}

__global__ __launch_bounds__(256) void fill_csr_part(const void* __restrict__ ei,
                                                     const int* __restrict__ flag,
                                                     int* __restrict__ cursor,
                                                     ushort* __restrict__ csr,
                                                     int E, int M, int nslice) {
    int p = blockIdx.x & (NP - 1);
    int slice = blockIdx.x >> 3;
    int psz = (M + NP - 1) / NP;
    int lo = p * psz, hi = min(M, lo + psz);
    int eps = (E + nslice - 1) / nslice;
    int e0 = slice * eps, e1 = min(E, e0 + eps);
    int sh = *flag;
    const int* sp = (const int*)ei;
    const int* dp = sp + ((long long)E << sh);
    for (int e = e0 + threadIdx.x; e < e1; e += 256) {
        int d = dp[e << sh];
        if (d >= lo && d < hi) {
            int s = sp[e << sh];
            int pos = atomicAdd(&cursor[d], 1);
            csr[pos] = (ushort)s;
        }
    }
}

__global__ __launch_bounds__(256) void block_sums(const int* __restrict__ cnt,
                                                  int* __restrict__ bsum, int n) {
    __shared__ int sm[256];
    int i = blockIdx.x * 256 + threadIdx.x;
    sm[threadIdx.x] = (i < n) ? cnt[i] : 0;
    __syncthreads();
    for (int off = 128; off > 0; off >>= 1) {
        if (threadIdx.x < off) sm[threadIdx.x] += sm[threadIdx.x + off];
        __syncthreads();
    }
    if (threadIdx.x == 0) bsum[blockIdx.x] = sm[0];
}

__global__ __launch_bounds__(64) void scan_bsums(int* __restrict__ bsum, int nb) {
    int lane = threadIdx.x;
    int per = (nb + 63) / 64;
    int loc[8];
    int s = 0;
    for (int k = 0; k < per; ++k) {
        int v = (lane * per + k < nb) ? bsum[lane * per + k] : 0;
        loc[k] = s;
        s += v;
    }
    int incl = s;
    for (int off = 1; off < 64; off <<= 1) {
        int t = __shfl_up(incl, off);
        if (lane >= off) incl += t;
    }
    int ex = incl - s;
    for (int k = 0; k < per; ++k)
        if (lane * per + k < nb) bsum[lane * per + k] = ex + loc[k];
}

__global__ __launch_bounds__(256) void block_scan_apply(const int* __restrict__ cnt,
                                                        const int* __restrict__ bsum,
                                                        int* __restrict__ offs,
                                                        int* __restrict__ cursor, int n) {
    __shared__ int sm[256];
    int i = blockIdx.x * 256 + threadIdx.x;
    int v = (i < n) ? cnt[i] : 0;
    sm[threadIdx.x] = v;
    __syncthreads();
    for (int off = 1; off < 256; off <<= 1) {
        int t = (threadIdx.x >= off) ? sm[threadIdx.x - off] : 0;
        __syncthreads();
        sm[threadIdx.x] += t;
        __syncthreads();
    }
    int excl = bsum[blockIdx.x] + sm[threadIdx.x] - v;
    if (i < n) {
        offs[i] = excl;
        cursor[i] = excl;
    }
}

// ---------------------------------------------------------------------------
// x (fp32 row-major) -> chunked fp16 [4][M][32]
// ---------------------------------------------------------------------------
__global__ __launch_bounds__(256) void convert_x(const float* __restrict__ x,
                                                 ushort* __restrict__ Xc, int M) {
    long long gid = (long long)blockIdx.x * 256 + threadIdx.x;
    if (gid >= (long long)M * 64) return;
    int node = (int)(gid >> 6), c2 = (int)(gid & 63);
    float2 v = *(const float2*)(x + (size_t)node * D + c2 * 2);
    int chunk = c2 >> 4;
    ((uint*)Xc)[(size_t)chunk * M * 16 + (size_t)node * 16 + (c2 & 15)] = pack2h(v.x, v.y);
}

// ---------------------------------------------------------------------------
// Pack weights (fp32 [128][128]) into fp16 MFMA B-fragment order:
// P[((ks*128 + n)*4 + g)*8 + j] = W[(ks*32+g*8+j)*128 + n]
// ---------------------------------------------------------------------------
__global__ __launch_bounds__(256) void pack_weights(const float* __restrict__ W0,
                                                    const float* __restrict__ W1,
                                                    const float* __restrict__ W2,
                                                    const float* __restrict__ W3,
                                                    ushort* __restrict__ P0,
                                                    ushort* __restrict__ P1,
                                                    ushort* __restrict__ P2,
                                                    ushort* __restrict__ P3) {
    int o = (blockIdx.x & 63) * 256 + threadIdx.x;  // 0..16383
    int which = blockIdx.x >> 6;
    const float* W = which == 0 ? W0 : which == 1 ? W1 : which == 2 ? W2 : W3;
    ushort* P = which == 0 ? P0 : which == 1 ? P1 : which == 2 ? P2 : P3;
    int j = o & 7, g = (o >> 3) & 3, n = (o >> 5) & 127, ks = o >> 12;
    int k = ks * 32 + g * 8 + j;
    __half h = __float2half_rn(W[k * 128 + n]);
    P[o] = *(ushort*)&h;
}

// ---------------------------------------------------------------------------
// Gather-aggregate, one wave per NODE (all 4 chunks at once).
// Lane = (chunk = lane>>4, col = lane&15); an edge's full 256B row is loaded
// by the whole wave in one instruction. node + edge indices are wave-uniform
// scalars; no cross-lane reduction. 8 edges in flight. csr is ushort.
// ---------------------------------------------------------------------------
__global__ __launch_bounds__(256) void aggregate_f16(const ushort* __restrict__ Xc,
                                                     const int* __restrict__ offs,
                                                     const int* __restrict__ cnt,
                                                     const ushort* __restrict__ csr,
                                                     ushort* __restrict__ Hc, int M) {
    int wv = __builtin_amdgcn_readfirstlane((int)(threadIdx.x >> 6));
    int node = blockIdx.x * 4 + wv;
    if (node >= M) return;
    int lane = threadIdx.x & 63;
    int chunk = lane >> 4, c16 = lane & 15;
    int vo = chunk * (M * 16) + c16;              // lane-constant element offset
    const uint* X = (const uint*)Xc;

    int beg = offs[node], deg = cnt[node];
    const ushort* ep = csr + beg;

    __half2 acc = u2h(X[(size_t)node * 16 + vo]);   // self term
    for (int j0 = 0; j0 < deg; j0 += 8) {
        int es[8];
        uint us[8];
#pragma unroll
        for (int k = 0; k < 8; ++k) {
            int e = j0 + k;
            es[k] = ep[e < deg ? e : 0];            // uniform index loads
        }
#pragma unroll
        for (int k = 0; k < 8; ++k)
            us[k] = X[(size_t)es[k] * 16 + vo];     // wave-wide 256B row gather
#pragma unroll
        for (int k = 0; k < 8; ++k)
            us[k] = (j0 + k < deg) ? us[k] : 0u;
        __half2 s0 = __hadd2(u2h(us[0]), u2h(us[1]));
        __half2 s1 = __hadd2(u2h(us[2]), u2h(us[3]));
        __half2 s2 = __hadd2(u2h(us[4]), u2h(us[5]));
        __half2 s3 = __hadd2(u2h(us[6]), u2h(us[7]));
        s0 = __hadd2(s0, s1);
        s2 = __hadd2(s2, s3);
        acc = __hadd2(acc, __hadd2(s0, s2));
    }
    ((uint*)Hc)[(size_t)node * 16 + vo] = h2u(acc);
}

// ---------------------------------------------------------------------------
// Fused MLP: C = relu(relu(A@Wa+ba)@Wb+bb)  (FINAL: out = sigmoid(C@Wfc+bfc)).
// 128 rows/block: each wave handles TWO 16-row tiles so the 64KB of staged
// weights is reused 2x and block count halves. LDS = 32KB sB + 32KB Hs ->
// 2 blocks/CU. A fragments for both tiles prefetched before staging.
// ---------------------------------------------------------------------------
template <int FINAL>
__global__ __launch_bounds__(256) void mlp_mfma(const ushort* __restrict__ A,
                                                const ushort* __restrict__ Bpa,
                                                const float* __restrict__ ba,
                                                const ushort* __restrict__ Bpb,
                                                const float* __restrict__ bb,
                                                const float* __restrict__ Wfc,
                                                const float* __restrict__ bfc,
                                                ushort* __restrict__ C,
                                                float* __restrict__ out, int M) {
    __shared__ ushort sB[16384];              // 32 KB: current packed weight matrix
    __shared__ ushort Hs[2][4][16][16][8];    // 32 KB: per-wave 16x128 tiles (x2)
    int t = threadIdx.x;
    int wv = t >> 6, lane = t & 63;
    int l15 = lane & 15, g = lane >> 4;
    int rb0 = blockIdx.x * 128 + wv * 16;

    // prefetch A fragments for both tiles (latency hides under Wa staging)
    half8 a_frag[2][4];
#pragma unroll
    for (int h = 0; h < 2; ++h) {
        int arow = rb0 + h * 64 + l15;
        int arow_c = arow < M ? arow : M - 1;
#pragma unroll
        for (int ks = 0; ks < 4; ++ks)
            a_frag[h][ks] = *(const half8*)(A + (size_t)ks * M * 32 + (size_t)arow_c * 32 + g * 8);
    }

    // stage Wa fragments
    for (int i = t; i < 2048; i += 256) ((uint4*)sB)[i] = ((const uint4*)Bpa)[i];
    __syncthreads();

    // ---- GEMM 1 (both tiles) -> relu -> swizzled LDS
#pragma unroll
    for (int h = 0; h < 2; ++h) {
        f32x4 acc[8];
#pragma unroll
        for (int i = 0; i < 8; ++i) acc[i] = (f32x4){0.f, 0.f, 0.f, 0.f};
#pragma unroll
        for (int ks = 0; ks < 4; ++ks) {
#pragma unroll
            for (int nt = 0; nt < 8; ++nt) {
                half8 b = *(const half8*)&sB[((ks * 128 + nt * 16 + l15) * 4 + g) << 3];
                acc[nt] = __builtin_amdgcn_mfma_f32_16x16x32_f16(a_frag[h][ks], b, acc[nt], 0, 0, 0);
            }
        }
#pragma unroll
        for (int nt = 0; nt < 8; ++nt) {
            int col = nt * 16 + l15;
            float bv = ba[col];
            int u = col >> 3, j = col & 7;
#pragma unroll
            for (int r = 0; r < 4; ++r) {
                int row = g * 4 + r;
                float v = fmaxf(acc[nt][r] + bv, 0.f);
                __half hh = __float2half_rn(v);
                Hs[h][wv][row][u ^ row][j] = *(ushort*)&hh;
            }
        }
    }
    __syncthreads();

    // stage Wb fragments (sB reuse; all waves done reading Wa)
    for (int i = t; i < 2048; i += 256) ((uint4*)sB)[i] = ((const uint4*)Bpb)[i];
    __syncthreads();

    // ---- GEMM 2 (both tiles)
#pragma unroll
    for (int h = 0; h < 2; ++h) {
        f32x4 acc2[8];
#pragma unroll
        for (int i = 0; i < 8; ++i) acc2[i] = (f32x4){0.f, 0.f, 0.f, 0.f};
#pragma unroll
        for (int ks = 0; ks < 4; ++ks) {
            half8 a = *(const half8*)&Hs[h][wv][l15][(ks * 4 + g) ^ l15][0];
#pragma unroll
            for (int nt = 0; nt < 8; ++nt) {
                half8 b = *(const half8*)&sB[((ks * 128 + nt * 16 + l15) * 4 + g) << 3];
                acc2[nt] = __builtin_amdgcn_mfma_f32_16x16x32_f16(a, b, acc2[nt], 0, 0, 0);
            }
        }

        if (!FINAL) {
#pragma unroll
            for (int nt = 0; nt < 8; ++nt) {
                int col = nt * 16 + l15;
                float bv = bb[col];
                int chunk = col >> 5, cc = col & 31;
#pragma unroll
                for (int r = 0; r < 4; ++r) {
                    int row = rb0 + h * 64 + g * 4 + r;
                    if (row < M) {
                        float v = fmaxf(acc2[nt][r] + bv, 0.f);
                        __half hh = __float2half_rn(v);
                        C[(size_t)chunk * M * 32 + (size_t)row * 32 + cc] = *(ushort*)&hh;
                    }
                }
            }
        } else {
            float p[4] = {0.f, 0.f, 0.f, 0.f};
#pragma unroll
            for (int nt = 0; nt < 8; ++nt) {
                int col = nt * 16 + l15;
                float bv = bb[col];
                float wf = Wfc[col];
#pragma unroll
                for (int r = 0; r < 4; ++r) {
                    float v = fmaxf(acc2[nt][r] + bv, 0.f);
                    p[r] = fmaf(v, wf, p[r]);
                }
            }
#pragma unroll
            for (int r = 0; r < 4; ++r) {
                p[r] += __shfl_xor(p[r], 1);
                p[r] += __shfl_xor(p[r], 2);
                p[r] += __shfl_xor(p[r], 4);
                p[r] += __shfl_xor(p[r], 8);
            }
            if (l15 == 0) {
                float bf = bfc[0];
#pragma unroll
                for (int r = 0; r < 4; ++r) {
                    int row = rb0 + h * 64 + g * 4 + r;
                    if (row < M) out[row] = 1.f / (1.f + expf(-(p[r] + bf)));
                }
            }
        }
    }
}

extern "C" void kernel_launch(void* const* d_in, const int* in_sizes, int n_in,
                              void* d_out, int out_size, void* d_ws, size_t ws_size,
                              hipStream_t stream) {
    const float* x   = (const float*)d_in[0];
    const void*  ei  = d_in[1];
    const float* W1a = (const float*)d_in[2];
    const float* b1a = (const float*)d_in[3];
    const float* W1b = (const float*)d_in[4];
    const float* b1b = (const float*)d_in[5];
    const float* W2a = (const float*)d_in[6];
    const float* b2a = (const float*)d_in[7];
    const float* W2b = (const float*)d_in[8];
    const float* b2b = (const float*)d_in[9];
    const float* Wfc = (const float*)d_in[10];
    const float* bfc = (const float*)d_in[11];
    float* out = (float*)d_out;

    int M = in_sizes[0] / D;   // 50000
    int E = in_sizes[1] / 2;   // 800000
    size_t nf = (size_t)M * D;

    // workspace layout
    ushort* B0 = (ushort*)d_ws;          // chunked fp16 [4][M][32]
    ushort* B1 = B0 + nf;
    ushort* B2 = B1 + nf;
    ushort* P1a = B2 + nf;               // 4 x 16384 packed weights
    ushort* P1b = P1a + 16384;
    ushort* P2a = P1b + 16384;
    ushort* P2b = P2a + 16384;
    int* cnt    = (int*)(P2b + 16384);
    int* offs   = cnt + M;
    int* cursor = offs + M;
    ushort* csr = (ushort*)(cursor + M);
    int* flag   = (int*)(csr + ((E + 1) & ~1));
    int nb = (M + 255) / 256;
    int* bsum   = flag + 1;

    int mBlocks = (M + 255) / 256;
    int cvtBlocks = (int)(((long long)M * 64 + 255) / 256);
    int aggBlocks = (M + 3) / 4;
    dim3 mlpGrid((M + 127) / 128);
    int nslice = 256;                    // partitioned CSR grid = NP * nslice

    // ---- CSR build (once)
    zero_detect<<<mBlocks, 256, 0, stream>>>(cnt, M, (const unsigned int*)ei, flag);
    count_edges_part<<<NP * nslice, 256, 0, stream>>>(ei, flag, cnt, E, M, nslice);
    block_sums<<<nb, 256, 0, stream>>>(cnt, bsum, M);
    scan_bsums<<<1, 64, 0, stream>>>(bsum, nb);
    block_scan_apply<<<nb, 256, 0, stream>>>(cnt, bsum, offs, cursor, M);
    fill_csr_part<<<NP * nslice, 256, 0, stream>>>(ei, flag, cursor, csr, E, M, nslice);

    // ---- precompute fp16 inputs / packed weights
    convert_x<<<cvtBlocks, 256, 0, stream>>>(x, B0, M);
    pack_weights<<<256, 256, 0, stream>>>(W1a, W1b, W2a, W2b, P1a, P1b, P2a, P2b);

    // ---- layer 1
    aggregate_f16<<<aggBlocks, 256, 0, stream>>>(B0, offs, cnt, csr, B1, M);
    mlp_mfma<0><<<mlpGrid, 256, 0, stream>>>(B1, P1a, b1a, P1b, b1b, nullptr, nullptr, B2, nullptr, M);

    // ---- layer 2
    aggregate_f16<<<aggBlocks, 256, 0, stream>>>(B2, offs, cnt, csr, B0, M);
    mlp_mfma<1><<<mlpGrid, 256, 0, stream>>>(B0, P2a, b2a, P2b, b2b, Wfc, bfc, nullptr, out, M);
}

// Round 8
// 187.026 us; speedup vs baseline: 15.3880x; 1.1810x over previous
//
#include <hip/hip_runtime.h>
#include <hip/hip_fp16.h>
#include <cstdint>
#include <cstddef>

#define D 128
#define NP 8   // dst partitions == XCD count
typedef __attribute__((ext_vector_type(8))) _Float16 half8;
typedef __attribute__((ext_vector_type(4))) float f32x4;

__device__ __forceinline__ uint pack2h(float x, float y) {
    __half2 h = __floats2half2_rn(x, y);
    return *(uint*)&h;
}
__device__ __forceinline__ __half2 u2h(uint u) { return *(__half2*)&u; }
__device__ __forceinline__ uint h2u(__half2 h) { return *(uint*)&h; }

// ---------------------------------------------------------------------------
// zero degree counters + edge dtype probe + zero the sentinel rows (row M)
// of the two buffers the aggregate reads (B0, B2).
// ---------------------------------------------------------------------------
__global__ __launch_bounds__(256) void zero_detect(int* __restrict__ cnt, int n,
                                                   const unsigned int* __restrict__ ei,
                                                   int* __restrict__ flag,
                                                   uint* __restrict__ zrow0,
                                                   uint* __restrict__ zrow2, int M) {
    int i = blockIdx.x * 256 + threadIdx.x;
    if (i < n) cnt[i] = 0;
    if (blockIdx.x == 0 && threadIdx.x < 64) {
        zrow0[(size_t)M * 64 + threadIdx.x] = 0u;
        zrow2[(size_t)M * 64 + threadIdx.x] = 0u;
        if (threadIdx.x == 0) {
            int is64 = (ei[1] == 0u && ei[3] == 0u && ei[5] == 0u && ei[7] == 0u) ? 1 : 0;
            *flag = is64;
        }
    }
}

// ---------------------------------------------------------------------------
// Partitioned CSR build: blockIdx&7 = dst partition -> XCD-local atomics.
// ---------------------------------------------------------------------------
__global__ __launch_bounds__(256) void count_edges_part(const void* __restrict__ ei,
                                                        const int* __restrict__ flag,
                                                        int* __restrict__ cnt,
                                                        int E, int M, int nslice) {
    int p = blockIdx.x & (NP - 1);
    int slice = blockIdx.x >> 3;
    int psz = (M + NP - 1) / NP;
    int lo = p * psz, hi = min(M, lo + psz);
    int eps = (E + nslice - 1) / nslice;
    int e0 = slice * eps, e1 = min(E, e0 + eps);
    int sh = *flag;
    const int* dp = (const int*)ei + ((long long)E << sh);
    for (int e = e0 + threadIdx.x; e < e1; e += 256) {
        int d = dp[e << sh];
        if (d >= lo && d < hi) atomicAdd(&cnt[d], 1);
    }
}

__global__ __launch_bounds__(256) void fill_csr_part(const void* __restrict__ ei,
                                                     const int* __restrict__ flag,
                                                     int* __restrict__ cursor,
                                                     ushort* __restrict__ csr,
                                                     int E, int M, int nslice) {
    int p = blockIdx.x & (NP - 1);
    int slice = blockIdx.x >> 3;
    int psz = (M + NP - 1) / NP;
    int lo = p * psz, hi = min(M, lo + psz);
    int eps = (E + nslice - 1) / nslice;
    int e0 = slice * eps, e1 = min(E, e0 + eps);
    int sh = *flag;
    const int* sp = (const int*)ei;
    const int* dp = sp + ((long long)E << sh);
    for (int e = e0 + threadIdx.x; e < e1; e += 256) {
        int d = dp[e << sh];
        if (d >= lo && d < hi) {
            int s = sp[e << sh];
            int pos = atomicAdd(&cursor[d], 1);
            csr[pos] = (ushort)s;
        }
    }
}

// scans use degree padded to multiple of 16 (aligned uint4 index loads +
// fixed 16-deep gather pipeline, sentinel-padded)
__device__ __forceinline__ int pad16(int v) { return (v + 15) & ~15; }

__global__ __launch_bounds__(256) void block_sums(const int* __restrict__ cnt,
                                                  int* __restrict__ bsum, int n) {
    __shared__ int sm[256];
    int i = blockIdx.x * 256 + threadIdx.x;
    sm[threadIdx.x] = (i < n) ? pad16(cnt[i]) : 0;
    __syncthreads();
    for (int off = 128; off > 0; off >>= 1) {
        if (threadIdx.x < off) sm[threadIdx.x] += sm[threadIdx.x + off];
        __syncthreads();
    }
    if (threadIdx.x == 0) bsum[blockIdx.x] = sm[0];
}

__global__ __launch_bounds__(64) void scan_bsums(int* __restrict__ bsum, int nb) {
    int lane = threadIdx.x;
    int per = (nb + 63) / 64;
    int loc[8];
    int s = 0;
    for (int k = 0; k < per; ++k) {
        int v = (lane * per + k < nb) ? bsum[lane * per + k] : 0;
        loc[k] = s;
        s += v;
    }
    int incl = s;
    for (int off = 1; off < 64; off <<= 1) {
        int t = __shfl_up(incl, off);
        if (lane >= off) incl += t;
    }
    int ex = incl - s;
    for (int k = 0; k < per; ++k)
        if (lane * per + k < nb) bsum[lane * per + k] = ex + loc[k];
}

__global__ __launch_bounds__(256) void block_scan_apply(const int* __restrict__ cnt,
                                                        const int* __restrict__ bsum,
                                                        int* __restrict__ offs,
                                                        int* __restrict__ cursor, int n) {
    __shared__ int sm[256];
    int i = blockIdx.x * 256 + threadIdx.x;
    int v = (i < n) ? pad16(cnt[i]) : 0;
    sm[threadIdx.x] = v;
    __syncthreads();
    for (int off = 1; off < 256; off <<= 1) {
        int t = (threadIdx.x >= off) ? sm[threadIdx.x - off] : 0;
        __syncthreads();
        sm[threadIdx.x] += t;
        __syncthreads();
    }
    int excl = bsum[blockIdx.x] + sm[threadIdx.x] - v;
    if (i < n) {
        offs[i] = excl;
        cursor[i] = excl;
    }
}

// write sentinel (node M -> zero row) into the padding slots
__global__ __launch_bounds__(256) void pad_csr(const int* __restrict__ offs,
                                               const int* __restrict__ cnt,
                                               ushort* __restrict__ csr, int M) {
    int i = blockIdx.x * 256 + threadIdx.x;
    if (i >= M) return;
    int beg = offs[i], deg = cnt[i], degp = pad16(deg);
    for (int j = deg; j < degp; ++j) csr[beg + j] = (ushort)M;
}

// ---------------------------------------------------------------------------
// x (fp32 row-major) -> fp16 row-major [M+1][128]
// ---------------------------------------------------------------------------
__global__ __launch_bounds__(256) void convert_x(const float* __restrict__ x,
                                                 uint* __restrict__ X32, int M) {
    long long gid = (long long)blockIdx.x * 256 + threadIdx.x;
    if (gid >= (long long)M * 64) return;
    int node = (int)(gid >> 6), c = (int)(gid & 63);
    float2 v = *(const float2*)(x + (size_t)node * D + c * 2);
    X32[(size_t)node * 64 + c] = pack2h(v.x, v.y);
}

// ---------------------------------------------------------------------------
// Pack weights (fp32 [128][128]) into fp16 MFMA B-fragment order:
// P[((ks*128 + n)*4 + g)*8 + j] = W[(ks*32+g*8+j)*128 + n]
// ---------------------------------------------------------------------------
__global__ __launch_bounds__(256) void pack_weights(const float* __restrict__ W0,
                                                    const float* __restrict__ W1,
                                                    const float* __restrict__ W2,
                                                    const float* __restrict__ W3,
                                                    ushort* __restrict__ P0,
                                                    ushort* __restrict__ P1,
                                                    ushort* __restrict__ P2,
                                                    ushort* __restrict__ P3) {
    int o = (blockIdx.x & 63) * 256 + threadIdx.x;  // 0..16383
    int which = blockIdx.x >> 6;
    const float* W = which == 0 ? W0 : which == 1 ? W1 : which == 2 ? W2 : W3;
    ushort* P = which == 0 ? P0 : which == 1 ? P1 : which == 2 ? P2 : P3;
    int j = o & 7, g = (o >> 3) & 3, n = (o >> 5) & 127, ks = o >> 12;
    int k = ks * 32 + g * 8 + j;
    __half h = __float2half_rn(W[k * 128 + n]);
    P[o] = *(ushort*)&h;
}

// ---------------------------------------------------------------------------
// Gather-aggregate, one wave per node, row-major [M+1][128] fp16.
// Each edge gather = one contiguous 256B row (64 lanes x 4B). Edge lists are
// sentinel-padded to multiples of 16 -> no masking, aligned uint4 index loads
// (scalar path), fixed 16 gathers in flight (4KB/wave).
// ---------------------------------------------------------------------------
__global__ __launch_bounds__(256) void aggregate_f16(const uint* __restrict__ X,
                                                     const int* __restrict__ offs,
                                                     const int* __restrict__ cnt,
                                                     const ushort* __restrict__ csr,
                                                     uint* __restrict__ H, int M) {
    int wv = __builtin_amdgcn_readfirstlane((int)(threadIdx.x >> 6));
    int node = blockIdx.x * 4 + wv;
    if (node >= M) return;
    int lane = threadIdx.x & 63;

    int beg = __builtin_amdgcn_readfirstlane(offs[node]);
    int degp = pad16(__builtin_amdgcn_readfirstlane(cnt[node]));
    const ushort* ep = csr + beg;

    __half2 acc = u2h(X[(size_t)node * 64 + lane]);   // self term
    for (int j0 = 0; j0 < degp; j0 += 16) {
        uint4 i0 = *(const uint4*)(ep + j0);          // 8 indices (16B aligned)
        uint4 i1 = *(const uint4*)(ep + j0 + 8);      // 8 indices
        uint us[16];
        us[0]  = X[(size_t)(i0.x & 0xffff) * 64 + lane];
        us[1]  = X[(size_t)(i0.x >> 16)    * 64 + lane];
        us[2]  = X[(size_t)(i0.y & 0xffff) * 64 + lane];
        us[3]  = X[(size_t)(i0.y >> 16)    * 64 + lane];
        us[4]  = X[(size_t)(i0.z & 0xffff) * 64 + lane];
        us[5]  = X[(size_t)(i0.z >> 16)    * 64 + lane];
        us[6]  = X[(size_t)(i0.w & 0xffff) * 64 + lane];
        us[7]  = X[(size_t)(i0.w >> 16)    * 64 + lane];
        us[8]  = X[(size_t)(i1.x & 0xffff) * 64 + lane];
        us[9]  = X[(size_t)(i1.x >> 16)    * 64 + lane];
        us[10] = X[(size_t)(i1.y & 0xffff) * 64 + lane];
        us[11] = X[(size_t)(i1.y >> 16)    * 64 + lane];
        us[12] = X[(size_t)(i1.z & 0xffff) * 64 + lane];
        us[13] = X[(size_t)(i1.z >> 16)    * 64 + lane];
        us[14] = X[(size_t)(i1.w & 0xffff) * 64 + lane];
        us[15] = X[(size_t)(i1.w >> 16)    * 64 + lane];
        __half2 t0 = __hadd2(__hadd2(u2h(us[0]), u2h(us[1])), __hadd2(u2h(us[2]), u2h(us[3])));
        __half2 t1 = __hadd2(__hadd2(u2h(us[4]), u2h(us[5])), __hadd2(u2h(us[6]), u2h(us[7])));
        __half2 t2 = __hadd2(__hadd2(u2h(us[8]), u2h(us[9])), __hadd2(u2h(us[10]), u2h(us[11])));
        __half2 t3 = __hadd2(__hadd2(u2h(us[12]), u2h(us[13])), __hadd2(u2h(us[14]), u2h(us[15])));
        acc = __hadd2(acc, __hadd2(__hadd2(t0, t1), __hadd2(t2, t3)));
    }
    H[(size_t)node * 64 + lane] = h2u(acc);
}

// ---------------------------------------------------------------------------
// Fused MLP: C = relu(relu(A@Wa+ba)@Wb+bb)  (FINAL: out = sigmoid(C@Wfc+bfc)).
// A, C row-major fp16 [M+1][128]. 128 rows/block, weights staged in LDS once
// per matrix, intermediate tiles in XOR-swizzled LDS.
// ---------------------------------------------------------------------------
template <int FINAL>
__global__ __launch_bounds__(256) void mlp_mfma(const ushort* __restrict__ A,
                                                const ushort* __restrict__ Bpa,
                                                const float* __restrict__ ba,
                                                const ushort* __restrict__ Bpb,
                                                const float* __restrict__ bb,
                                                const float* __restrict__ Wfc,
                                                const float* __restrict__ bfc,
                                                ushort* __restrict__ C,
                                                float* __restrict__ out, int M) {
    __shared__ ushort sB[16384];              // 32 KB: current packed weight matrix
    __shared__ ushort Hs[2][4][16][16][8];    // 32 KB: per-wave 16x128 tiles (x2)
    int t = threadIdx.x;
    int wv = t >> 6, lane = t & 63;
    int l15 = lane & 15, g = lane >> 4;
    int rb0 = blockIdx.x * 128 + wv * 16;

    // prefetch A fragments for both tiles (latency hides under Wa staging)
    half8 a_frag[2][4];
#pragma unroll
    for (int h = 0; h < 2; ++h) {
        int arow = rb0 + h * 64 + l15;
        int arow_c = arow < M ? arow : M - 1;
#pragma unroll
        for (int ks = 0; ks < 4; ++ks)
            a_frag[h][ks] = *(const half8*)(A + (size_t)arow_c * D + ks * 32 + g * 8);
    }

    // stage Wa fragments
    for (int i = t; i < 2048; i += 256) ((uint4*)sB)[i] = ((const uint4*)Bpa)[i];
    __syncthreads();

    // ---- GEMM 1 (both tiles) -> relu -> swizzled LDS
#pragma unroll
    for (int h = 0; h < 2; ++h) {
        f32x4 acc[8];
#pragma unroll
        for (int i = 0; i < 8; ++i) acc[i] = (f32x4){0.f, 0.f, 0.f, 0.f};
#pragma unroll
        for (int ks = 0; ks < 4; ++ks) {
#pragma unroll
            for (int nt = 0; nt < 8; ++nt) {
                half8 b = *(const half8*)&sB[((ks * 128 + nt * 16 + l15) * 4 + g) << 3];
                acc[nt] = __builtin_amdgcn_mfma_f32_16x16x32_f16(a_frag[h][ks], b, acc[nt], 0, 0, 0);
            }
        }
#pragma unroll
        for (int nt = 0; nt < 8; ++nt) {
            int col = nt * 16 + l15;
            float bv = ba[col];
            int u = col >> 3, j = col & 7;
#pragma unroll
            for (int r = 0; r < 4; ++r) {
                int row = g * 4 + r;
                float v = fmaxf(acc[nt][r] + bv, 0.f);
                __half hh = __float2half_rn(v);
                Hs[h][wv][row][u ^ row][j] = *(ushort*)&hh;
            }
        }
    }
    __syncthreads();

    // stage Wb fragments (sB reuse; all waves done reading Wa)
    for (int i = t; i < 2048; i += 256) ((uint4*)sB)[i] = ((const uint4*)Bpb)[i];
    __syncthreads();

    // ---- GEMM 2 (both tiles)
#pragma unroll
    for (int h = 0; h < 2; ++h) {
        f32x4 acc2[8];
#pragma unroll
        for (int i = 0; i < 8; ++i) acc2[i] = (f32x4){0.f, 0.f, 0.f, 0.f};
#pragma unroll
        for (int ks = 0; ks < 4; ++ks) {
            half8 a = *(const half8*)&Hs[h][wv][l15][(ks * 4 + g) ^ l15][0];
#pragma unroll
            for (int nt = 0; nt < 8; ++nt) {
                half8 b = *(const half8*)&sB[((ks * 128 + nt * 16 + l15) * 4 + g) << 3];
                acc2[nt] = __builtin_amdgcn_mfma_f32_16x16x32_f16(a, b, acc2[nt], 0, 0, 0);
            }
        }

        if (!FINAL) {
#pragma unroll
            for (int nt = 0; nt < 8; ++nt) {
                int col = nt * 16 + l15;
                float bv = bb[col];
#pragma unroll
                for (int r = 0; r < 4; ++r) {
                    int row = rb0 + h * 64 + g * 4 + r;
                    if (row < M) {
                        float v = fmaxf(acc2[nt][r] + bv, 0.f);
                        __half hh = __float2half_rn(v);
                        C[(size_t)row * D + col] = *(ushort*)&hh;
                    }
                }
            }
        } else {
            float p[4] = {0.f, 0.f, 0.f, 0.f};
#pragma unroll
            for (int nt = 0; nt < 8; ++nt) {
                int col = nt * 16 + l15;
                float bv = bb[col];
                float wf = Wfc[col];
#pragma unroll
                for (int r = 0; r < 4; ++r) {
                    float v = fmaxf(acc2[nt][r] + bv, 0.f);
                    p[r] = fmaf(v, wf, p[r]);
                }
            }
#pragma unroll
            for (int r = 0; r < 4; ++r) {
                p[r] += __shfl_xor(p[r], 1);
                p[r] += __shfl_xor(p[r], 2);
                p[r] += __shfl_xor(p[r], 4);
                p[r] += __shfl_xor(p[r], 8);
            }
            if (l15 == 0) {
                float bf = bfc[0];
#pragma unroll
                for (int r = 0; r < 4; ++r) {
                    int row = rb0 + h * 64 + g * 4 + r;
                    if (row < M) out[row] = 1.f / (1.f + expf(-(p[r] + bf)));
                }
            }
        }
    }
}

extern "C" void kernel_launch(void* const* d_in, const int* in_sizes, int n_in,
                              void* d_out, int out_size, void* d_ws, size_t ws_size,
                              hipStream_t stream) {
    const float* x   = (const float*)d_in[0];
    const void*  ei  = d_in[1];
    const float* W1a = (const float*)d_in[2];
    const float* b1a = (const float*)d_in[3];
    const float* W1b = (const float*)d_in[4];
    const float* b1b = (const float*)d_in[5];
    const float* W2a = (const float*)d_in[6];
    const float* b2a = (const float*)d_in[7];
    const float* W2b = (const float*)d_in[8];
    const float* b2b = (const float*)d_in[9];
    const float* Wfc = (const float*)d_in[10];
    const float* bfc = (const float*)d_in[11];
    float* out = (float*)d_out;

    int M = in_sizes[0] / D;   // 50000
    int E = in_sizes[1] / 2;   // 800000
    size_t nf2 = (size_t)(M + 1) * D;    // rows incl. zero sentinel row

    // workspace layout
    ushort* B0 = (ushort*)d_ws;          // fp16 row-major [M+1][128]
    ushort* B1 = B0 + nf2;
    ushort* B2 = B1 + nf2;
    ushort* P1a = B2 + nf2;              // 4 x 16384 packed weights
    ushort* P1b = P1a + 16384;
    ushort* P2a = P1b + 16384;
    ushort* P2b = P2a + 16384;
    int* cnt    = (int*)(P2b + 16384);
    int* offs   = cnt + M;
    int* cursor = offs + M;
    ushort* csr = (ushort*)(cursor + M); // E + 16*M ushorts (sentinel-padded)
    int* flag   = (int*)(csr + (((size_t)E + 16 * (size_t)M + 1) & ~1ull));
    int nb = (M + 255) / 256;
    int* bsum   = flag + 1;

    int mBlocks = (M + 255) / 256;
    int cvtBlocks = (int)(((long long)M * 64 + 255) / 256);
    int aggBlocks = (M + 3) / 4;
    dim3 mlpGrid((M + 127) / 128);
    int nslice = 256;                    // partitioned CSR grid = NP * nslice

    // ---- CSR build (once)
    zero_detect<<<mBlocks, 256, 0, stream>>>(cnt, M, (const unsigned int*)ei, flag,
                                             (uint*)B0, (uint*)B2, M);
    count_edges_part<<<NP * nslice, 256, 0, stream>>>(ei, flag, cnt, E, M, nslice);
    block_sums<<<nb, 256, 0, stream>>>(cnt, bsum, M);
    scan_bsums<<<1, 64, 0, stream>>>(bsum, nb);
    block_scan_apply<<<nb, 256, 0, stream>>>(cnt, bsum, offs, cursor, M);
    pad_csr<<<mBlocks, 256, 0, stream>>>(offs, cnt, csr, M);
    fill_csr_part<<<NP * nslice, 256, 0, stream>>>(ei, flag, cursor, csr, E, M, nslice);

    // ---- precompute fp16 inputs / packed weights
    convert_x<<<cvtBlocks, 256, 0, stream>>>(x, (uint*)B0, M);
    pack_weights<<<256, 256, 0, stream>>>(W1a, W1b, W2a, W2b, P1a, P1b, P2a, P2b);

    // ---- layer 1
    aggregate_f16<<<aggBlocks, 256, 0, stream>>>((const uint*)B0, offs, cnt, csr, (uint*)B1, M);
    mlp_mfma<0><<<mlpGrid, 256, 0, stream>>>(B1, P1a, b1a, P1b, b1b, nullptr, nullptr, B2, nullptr, M);

    // ---- layer 2
    aggregate_f16<<<aggBlocks, 256, 0, stream>>>((const uint*)B2, offs, cnt, csr, (uint*)B0, M);
    mlp_mfma<1><<<mlpGrid, 256, 0, stream>>>(B0, P2a, b2a, P2b, b2b, Wfc, bfc, nullptr, out, M);
}

// Round 11
// 183.184 us; speedup vs baseline: 15.7107x; 1.0210x over previous
//
#include <hip/hip_runtime.h>
#include <hip/hip_fp16.h>
#include <cstdint>
#include <cstddef>

#define D 128
#define NP 8   // dst partitions == XCD count
typedef __attribute__((ext_vector_type(8))) _Float16 half8;
typedef __attribute__((ext_vector_type(4))) float f32x4;
typedef __attribute__((ext_vector_type(4))) uint uint4n;   // native vec for NT builtins

__device__ __forceinline__ uint pack2h(float x, float y) {
    __half2 h = __floats2half2_rn(x, y);
    return *(uint*)&h;
}
__device__ __forceinline__ __half2 u2h(uint u) { return *(__half2*)&u; }
__device__ __forceinline__ uint h2u(__half2 h) { return *(uint*)&h; }
__device__ __forceinline__ int pad16(int v) { return (v + 15) & ~15; }

// ---------------------------------------------------------------------------
// prep: (blockIdx-partitioned)  convert_x | pack_weights | zero cnt + flag +
// sentinel rows.  All roles independent.
// ---------------------------------------------------------------------------
__global__ __launch_bounds__(256) void prep(const float* __restrict__ x,
                                            uint* __restrict__ X32,
                                            const float* __restrict__ W0,
                                            const float* __restrict__ W1,
                                            const float* __restrict__ W2,
                                            const float* __restrict__ W3,
                                            ushort* __restrict__ P0,
                                            ushort* __restrict__ P1,
                                            ushort* __restrict__ P2,
                                            ushort* __restrict__ P3,
                                            int* __restrict__ cnt,
                                            const unsigned int* __restrict__ ei,
                                            int* __restrict__ flag,
                                            uint* __restrict__ zrow0,
                                            uint* __restrict__ zrow2,
                                            int M, int cvtB, int mB) {
    int b = blockIdx.x, t = threadIdx.x;
    if (b < cvtB) {
        // convert: 8 halves (one uint4n) per thread
        long long gid = (long long)b * 256 + t;          // unit of 8 cols
        if (gid >= (long long)M * 16) return;
        int node = (int)(gid >> 4), q = (int)(gid & 15);
        const float4* xp = (const float4*)(x + (size_t)node * D + q * 8);
        float4 v0 = xp[0], v1 = xp[1];
        uint4n o;
        o.x = pack2h(v0.x, v0.y); o.y = pack2h(v0.z, v0.w);
        o.z = pack2h(v1.x, v1.y); o.w = pack2h(v1.z, v1.w);
        ((uint4n*)X32)[(size_t)node * 16 + q] = o;
    } else if (b < cvtB + 256) {
        // pack weights into MFMA B-fragment order
        int o = ((b - cvtB) & 63) * 256 + t;             // 0..16383
        int which = (b - cvtB) >> 6;
        const float* W = which == 0 ? W0 : which == 1 ? W1 : which == 2 ? W2 : W3;
        ushort* P = which == 0 ? P0 : which == 1 ? P1 : which == 2 ? P2 : P3;
        int j = o & 7, g = (o >> 3) & 3, n = (o >> 5) & 127, ks = o >> 12;
        int k = ks * 32 + g * 8 + j;
        __half h = __float2half_rn(W[k * 128 + n]);
        P[o] = *(ushort*)&h;
    } else {
        int i = (b - cvtB - 256) * 256 + t;
        if (i < M) cnt[i] = 0;
        if (b == cvtB + 256 && t < 64) {
            zrow0[(size_t)M * 64 + t] = 0u;
            zrow2[(size_t)M * 64 + t] = 0u;
            if (t == 0) {
                int is64 = (ei[1] == 0u && ei[3] == 0u && ei[5] == 0u && ei[7] == 0u) ? 1 : 0;
                *flag = is64;
            }
        }
    }
}

// ---------------------------------------------------------------------------
// Partitioned CSR build: blockIdx&7 = dst partition -> XCD-local atomics.
// ---------------------------------------------------------------------------
__global__ __launch_bounds__(256) void count_edges_part(const void* __restrict__ ei,
                                                        const int* __restrict__ flag,
                                                        int* __restrict__ cnt,
                                                        int E, int M, int nslice) {
    int p = blockIdx.x & (NP - 1);
    int slice = blockIdx.x >> 3;
    int psz = (M + NP - 1) / NP;
    int lo = p * psz, hi = min(M, lo + psz);
    int eps = (E + nslice - 1) / nslice;
    int e0 = slice * eps, e1 = min(E, e0 + eps);
    int sh = *flag;
    const int* dp = (const int*)ei + ((long long)E << sh);
    for (int e = e0 + threadIdx.x; e < e1; e += 256) {
        int d = dp[e << sh];
        if (d >= lo && d < hi) atomicAdd(&cnt[d], 1);
    }
}

__global__ __launch_bounds__(256) void fill_csr_part(const void* __restrict__ ei,
                                                     const int* __restrict__ flag,
                                                     int* __restrict__ cursor,
                                                     ushort* __restrict__ csr,
                                                     int E, int M, int nslice) {
    int p = blockIdx.x & (NP - 1);
    int slice = blockIdx.x >> 3;
    int psz = (M + NP - 1) / NP;
    int lo = p * psz, hi = min(M, lo + psz);
    int eps = (E + nslice - 1) / nslice;
    int e0 = slice * eps, e1 = min(E, e0 + eps);
    int sh = *flag;
    const int* sp = (const int*)ei;
    const int* dp = sp + ((long long)E << sh);
    for (int e = e0 + threadIdx.x; e < e1; e += 256) {
        int d = dp[e << sh];
        if (d >= lo && d < hi) {
            int s = sp[e << sh];
            int pos = atomicAdd(&cursor[d], 1);
            csr[pos] = (ushort)s;
        }
    }
}

__global__ __launch_bounds__(256) void block_sums(const int* __restrict__ cnt,
                                                  int* __restrict__ bsum, int n) {
    __shared__ int sm[256];
    int i = blockIdx.x * 256 + threadIdx.x;
    sm[threadIdx.x] = (i < n) ? pad16(cnt[i]) : 0;
    __syncthreads();
    for (int off = 128; off > 0; off >>= 1) {
        if (threadIdx.x < off) sm[threadIdx.x] += sm[threadIdx.x + off];
        __syncthreads();
    }
    if (threadIdx.x == 0) bsum[blockIdx.x] = sm[0];
}

__global__ __launch_bounds__(64) void scan_bsums(int* __restrict__ bsum, int nb) {
    int lane = threadIdx.x;
    int per = (nb + 63) / 64;
    int loc[8];
    int s = 0;
    for (int k = 0; k < per; ++k) {
        int v = (lane * per + k < nb) ? bsum[lane * per + k] : 0;
        loc[k] = s;
        s += v;
    }
    int incl = s;
    for (int off = 1; off < 64; off <<= 1) {
        int t = __shfl_up(incl, off);
        if (lane >= off) incl += t;
    }
    int ex = incl - s;
    for (int k = 0; k < per; ++k)
        if (lane * per + k < nb) bsum[lane * per + k] = ex + loc[k];
}

// scan apply + sentinel padding fused (thread i owns node i's pad slots)
__global__ __launch_bounds__(256) void block_scan_apply(const int* __restrict__ cnt,
                                                        const int* __restrict__ bsum,
                                                        int* __restrict__ offs,
                                                        int* __restrict__ cursor,
                                                        ushort* __restrict__ csr, int n) {
    __shared__ int sm[256];
    int i = blockIdx.x * 256 + threadIdx.x;
    int deg = (i < n) ? cnt[i] : 0;
    int v = pad16(deg);
    sm[threadIdx.x] = v;
    __syncthreads();
    for (int off = 1; off < 256; off <<= 1) {
        int t = (threadIdx.x >= off) ? sm[threadIdx.x - off] : 0;
        __syncthreads();
        sm[threadIdx.x] += t;
        __syncthreads();
    }
    int excl = bsum[blockIdx.x] + sm[threadIdx.x] - v;
    if (i < n) {
        offs[i] = excl;
        cursor[i] = excl;
        for (int j = deg; j < v; ++j) csr[excl + j] = (ushort)n;  // sentinel = M
    }
}

// ---------------------------------------------------------------------------
// Gather-aggregate, one wave per node, row-major [M+1][128] fp16.
// Sentinel-padded edge lists: no masking, aligned uint4 index loads, 16
// gathers in flight. H stored non-temporally (stream-once; keep X hot in L2).
// ---------------------------------------------------------------------------
__global__ __launch_bounds__(256) void aggregate_f16(const uint* __restrict__ X,
                                                     const int* __restrict__ offs,
                                                     const int* __restrict__ cnt,
                                                     const ushort* __restrict__ csr,
                                                     uint* __restrict__ H, int M) {
    int wv = __builtin_amdgcn_readfirstlane((int)(threadIdx.x >> 6));
    int node = blockIdx.x * 4 + wv;
    if (node >= M) return;
    int lane = threadIdx.x & 63;

    int beg = __builtin_amdgcn_readfirstlane(offs[node]);
    int degp = pad16(__builtin_amdgcn_readfirstlane(cnt[node]));
    const ushort* ep = csr + beg;

    __half2 acc = u2h(X[(size_t)node * 64 + lane]);   // self term
    for (int j0 = 0; j0 < degp; j0 += 16) {
        uint4n i0 = *(const uint4n*)(ep + j0);
        uint4n i1 = *(const uint4n*)(ep + j0 + 8);
        uint us[16];
        us[0]  = X[(size_t)(i0.x & 0xffff) * 64 + lane];
        us[1]  = X[(size_t)(i0.x >> 16)    * 64 + lane];
        us[2]  = X[(size_t)(i0.y & 0xffff) * 64 + lane];
        us[3]  = X[(size_t)(i0.y >> 16)    * 64 + lane];
        us[4]  = X[(size_t)(i0.z & 0xffff) * 64 + lane];
        us[5]  = X[(size_t)(i0.z >> 16)    * 64 + lane];
        us[6]  = X[(size_t)(i0.w & 0xffff) * 64 + lane];
        us[7]  = X[(size_t)(i0.w >> 16)    * 64 + lane];
        us[8]  = X[(size_t)(i1.x & 0xffff) * 64 + lane];
        us[9]  = X[(size_t)(i1.x >> 16)    * 64 + lane];
        us[10] = X[(size_t)(i1.y & 0xffff) * 64 + lane];
        us[11] = X[(size_t)(i1.y >> 16)    * 64 + lane];
        us[12] = X[(size_t)(i1.z & 0xffff) * 64 + lane];
        us[13] = X[(size_t)(i1.z >> 16)    * 64 + lane];
        us[14] = X[(size_t)(i1.w & 0xffff) * 64 + lane];
        us[15] = X[(size_t)(i1.w >> 16)    * 64 + lane];
        __half2 t0 = __hadd2(__hadd2(u2h(us[0]), u2h(us[1])), __hadd2(u2h(us[2]), u2h(us[3])));
        __half2 t1 = __hadd2(__hadd2(u2h(us[4]), u2h(us[5])), __hadd2(u2h(us[6]), u2h(us[7])));
        __half2 t2 = __hadd2(__hadd2(u2h(us[8]), u2h(us[9])), __hadd2(u2h(us[10]), u2h(us[11])));
        __half2 t3 = __hadd2(__hadd2(u2h(us[12]), u2h(us[13])), __hadd2(u2h(us[14]), u2h(us[15])));
        acc = __hadd2(acc, __hadd2(__hadd2(t0, t1), __hadd2(t2, t3)));
    }
    __builtin_nontemporal_store(h2u(acc), &H[(size_t)node * 64 + lane]);
}

// ---------------------------------------------------------------------------
// Persistent fused MLP: both weight matrices staged in LDS ONCE per block
// (64KB) + wave-private Hs (16KB) = 80KB -> 2 blocks/CU. Stride loop over
// 64-row tiles, ZERO per-tile barriers (Hs is wave-private; GEMM1->GEMM2
// ordering is just lgkmcnt). A-fragments loaded non-temporally (stream-once).
// A-fragment address: row*D + ks*32 + g*8 halves  (ks*4 uint4n from g*8 base).
// ---------------------------------------------------------------------------
template <int FINAL>
__global__ __launch_bounds__(256) void mlp_mfma(const ushort* __restrict__ A,
                                                const ushort* __restrict__ Bpa,
                                                const float* __restrict__ ba,
                                                const ushort* __restrict__ Bpb,
                                                const float* __restrict__ bb,
                                                const float* __restrict__ Wfc,
                                                const float* __restrict__ bfc,
                                                ushort* __restrict__ C,
                                                float* __restrict__ out,
                                                int M, int nTiles) {
    __shared__ ushort sB[2][16384];           // 64 KB: Wa, Wb packed fragments
    __shared__ ushort Hs[4][16][16][8];       // 16 KB: per-wave 16x128 tile
    int t = threadIdx.x;
    int wv = t >> 6, lane = t & 63;
    int l15 = lane & 15, g = lane >> 4;

    // stage both weight matrices once
    for (int i = t; i < 2048; i += 256) {
        ((uint4n*)sB[0])[i] = ((const uint4n*)Bpa)[i];
        ((uint4n*)sB[1])[i] = ((const uint4n*)Bpb)[i];
    }
    __syncthreads();

    float bva[8], bvb[8], wf[8];
#pragma unroll
    for (int nt = 0; nt < 8; ++nt) {
        bva[nt] = ba[nt * 16 + l15];
        bvb[nt] = bb[nt * 16 + l15];
        if (FINAL) wf[nt] = Wfc[nt * 16 + l15];
    }
    float bf = FINAL ? bfc[0] : 0.f;

    for (int tile = blockIdx.x; tile < nTiles; tile += gridDim.x) {
        int rb = tile * 64 + wv * 16;
        int arow = rb + l15;
        int arow_c = arow < M ? arow : M - 1;

        half8 a_frag[4];
        // base at row + g*8 halves; fragment ks at +ks*32 halves = +ks*4 uint4n
        const uint4n* ap = (const uint4n*)(A + (size_t)arow_c * D + g * 8);
#pragma unroll
        for (int ks = 0; ks < 4; ++ks) {
            uint4n u = __builtin_nontemporal_load(ap + ks * 4);
            a_frag[ks] = *(half8*)&u;
        }

        // ---- GEMM 1 -> relu -> swizzled wave-private LDS
        f32x4 acc[8];
#pragma unroll
        for (int i = 0; i < 8; ++i) acc[i] = (f32x4){0.f, 0.f, 0.f, 0.f};
#pragma unroll
        for (int ks = 0; ks < 4; ++ks) {
#pragma unroll
            for (int nt = 0; nt < 8; ++nt) {
                half8 b = *(const half8*)&sB[0][((ks * 128 + nt * 16 + l15) * 4 + g) << 3];
                acc[nt] = __builtin_amdgcn_mfma_f32_16x16x32_f16(a_frag[ks], b, acc[nt], 0, 0, 0);
            }
        }
#pragma unroll
        for (int nt = 0; nt < 8; ++nt) {
            int col = nt * 16 + l15;
            int u = col >> 3, j = col & 7;
#pragma unroll
            for (int r = 0; r < 4; ++r) {
                int row = g * 4 + r;
                float v = fmaxf(acc[nt][r] + bva[nt], 0.f);
                __half hh = __float2half_rn(v);
                Hs[wv][row][u ^ row][j] = *(ushort*)&hh;
            }
        }

        // ---- GEMM 2 (reads own wave's Hs; lgkmcnt ordering only)
        f32x4 acc2[8];
#pragma unroll
        for (int i = 0; i < 8; ++i) acc2[i] = (f32x4){0.f, 0.f, 0.f, 0.f};
#pragma unroll
        for (int ks = 0; ks < 4; ++ks) {
            half8 a = *(const half8*)&Hs[wv][l15][(ks * 4 + g) ^ l15][0];
#pragma unroll
            for (int nt = 0; nt < 8; ++nt) {
                half8 b = *(const half8*)&sB[1][((ks * 128 + nt * 16 + l15) * 4 + g) << 3];
                acc2[nt] = __builtin_amdgcn_mfma_f32_16x16x32_f16(a, b, acc2[nt], 0, 0, 0);
            }
        }

        if (!FINAL) {
#pragma unroll
            for (int nt = 0; nt < 8; ++nt) {
                int col = nt * 16 + l15;
#pragma unroll
                for (int r = 0; r < 4; ++r) {
                    int row = rb + g * 4 + r;
                    if (row < M) {
                        float v = fmaxf(acc2[nt][r] + bvb[nt], 0.f);
                        __half hh = __float2half_rn(v);
                        C[(size_t)row * D + col] = *(ushort*)&hh;
                    }
                }
            }
        } else {
            float p[4] = {0.f, 0.f, 0.f, 0.f};
#pragma unroll
            for (int nt = 0; nt < 8; ++nt) {
#pragma unroll
                for (int r = 0; r < 4; ++r) {
                    float v = fmaxf(acc2[nt][r] + bvb[nt], 0.f);
                    p[r] = fmaf(v, wf[nt], p[r]);
                }
            }
#pragma unroll
            for (int r = 0; r < 4; ++r) {
                p[r] += __shfl_xor(p[r], 1);
                p[r] += __shfl_xor(p[r], 2);
                p[r] += __shfl_xor(p[r], 4);
                p[r] += __shfl_xor(p[r], 8);
            }
            if (l15 == 0) {
#pragma unroll
                for (int r = 0; r < 4; ++r) {
                    int row = rb + g * 4 + r;
                    if (row < M) out[row] = 1.f / (1.f + expf(-(p[r] + bf)));
                }
            }
        }
    }
}

extern "C" void kernel_launch(void* const* d_in, const int* in_sizes, int n_in,
                              void* d_out, int out_size, void* d_ws, size_t ws_size,
                              hipStream_t stream) {
    const float* x   = (const float*)d_in[0];
    const void*  ei  = d_in[1];
    const float* W1a = (const float*)d_in[2];
    const float* b1a = (const float*)d_in[3];
    const float* W1b = (const float*)d_in[4];
    const float* b1b = (const float*)d_in[5];
    const float* W2a = (const float*)d_in[6];
    const float* b2a = (const float*)d_in[7];
    const float* W2b = (const float*)d_in[8];
    const float* b2b = (const float*)d_in[9];
    const float* Wfc = (const float*)d_in[10];
    const float* bfc = (const float*)d_in[11];
    float* out = (float*)d_out;

    int M = in_sizes[0] / D;   // 50000
    int E = in_sizes[1] / 2;   // 800000
    size_t nf2 = (size_t)(M + 1) * D;    // rows incl. zero sentinel row

    // workspace layout
    ushort* B0 = (ushort*)d_ws;          // fp16 row-major [M+1][128]
    ushort* B1 = B0 + nf2;
    ushort* B2 = B1 + nf2;
    ushort* P1a = B2 + nf2;              // 4 x 16384 packed weights
    ushort* P1b = P1a + 16384;
    ushort* P2a = P1b + 16384;
    ushort* P2b = P2a + 16384;
    int* cnt    = (int*)(P2b + 16384);
    int* offs   = cnt + M;
    int* cursor = offs + M;
    ushort* csr = (ushort*)(cursor + M); // E + 16*M ushorts (sentinel-padded)
    int* flag   = (int*)(csr + (((size_t)E + 16 * (size_t)M + 1) & ~1ull));
    int nb = (M + 255) / 256;
    int* bsum   = flag + 1;

    int mBlocks = (M + 255) / 256;
    int cvtB = (M * 16 + 255) / 256;
    int aggBlocks = (M + 3) / 4;
    int nTiles = (M + 63) / 64;
    int nslice = 256;                    // partitioned CSR grid = NP * nslice

    // ---- prep (convert + pack + zero/flag/sentinels)
    prep<<<cvtB + 256 + mBlocks, 256, 0, stream>>>(
        x, (uint*)B0, W1a, W1b, W2a, W2b, P1a, P1b, P2a, P2b,
        cnt, (const unsigned int*)ei, flag, (uint*)B0, (uint*)B2, M, cvtB, mBlocks);

    // ---- CSR build (once)
    count_edges_part<<<NP * nslice, 256, 0, stream>>>(ei, flag, cnt, E, M, nslice);
    block_sums<<<nb, 256, 0, stream>>>(cnt, bsum, M);
    scan_bsums<<<1, 64, 0, stream>>>(bsum, nb);
    block_scan_apply<<<nb, 256, 0, stream>>>(cnt, bsum, offs, cursor, csr, M);
    fill_csr_part<<<NP * nslice, 256, 0, stream>>>(ei, flag, cursor, csr, E, M, nslice);

    // ---- layer 1
    aggregate_f16<<<aggBlocks, 256, 0, stream>>>((const uint*)B0, offs, cnt, csr, (uint*)B1, M);
    mlp_mfma<0><<<512, 256, 0, stream>>>(B1, P1a, b1a, P1b, b1b, nullptr, nullptr, B2, nullptr, M, nTiles);

    // ---- layer 2
    aggregate_f16<<<aggBlocks, 256, 0, stream>>>((const uint*)B2, offs, cnt, csr, (uint*)B0, M);
    mlp_mfma<1><<<512, 256, 0, stream>>>(B0, P2a, b2a, P2b, b2b, Wfc, bfc, nullptr, out, M, nTiles);
}